// Round 5
// baseline (683.125 us; speedup 1.0000x reference)
//
#include <hip/hip_runtime.h>
#include <hip/hip_bf16.h>
#include <math.h>

// Problem constants (from reference)
#define NNODES 10000
#define MPAD   10112    // 79 * 128
#define EDGES  160000
#define EPLUS  170000   // EDGES + NNODES self-loops
#define FIN    512
#define HEADS8 8
#define CH     64
#define HC     512      // HEADS8*CH
#define NG     64       // graphs
#define NCLS   64
#define NPART  64       // bn partial blocks

typedef _Float16 f16x8 __attribute__((ext_vector_type(8)));
typedef _Float16 f16x4 __attribute__((ext_vector_type(4)));
typedef float    f32x4 __attribute__((ext_vector_type(4)));

#define GLD_LDS16(g, l)                                                        \
    __builtin_amdgcn_global_load_lds(                                          \
        (const __attribute__((address_space(1))) void*)(g),                    \
        (__attribute__((address_space(3))) void*)(l), 16, 0, 0)

// ---------------------------------------------------------------------------
// CSR build: histogram of dst (+ graph offsets fused), scan, scatter
// ---------------------------------------------------------------------------
__global__ void count_deg_goff(const int* __restrict__ ei, int* __restrict__ deg,
                               const int* __restrict__ batch, int* __restrict__ goff)
{
    int e = blockIdx.x * blockDim.x + threadIdx.x;
    if (e < NNODES) {  // graph boundary detection on sorted batch
        int b = batch[e];
        int bprev = (e == 0) ? -1 : batch[e - 1];
        for (int g = bprev + 1; g <= b; ++g) goff[g] = e;
        if (e == NNODES - 1)
            for (int g = b + 1; g <= NG; ++g) goff[g] = NNODES;
    }
    if (e >= EPLUS) return;
    int dst = (e < EDGES) ? ei[EDGES + e] : (e - EDGES);
    atomicAdd(&deg[dst], 1);
}

__global__ void exscan_deg(const int* __restrict__ deg, int* __restrict__ off,
                           int* __restrict__ cursor)
{
    __shared__ int partial[256];
    const int tid = threadIdx.x;
    const int chunk = (NNODES + 255) / 256; // 40
    int begin = tid * chunk;
    int end   = begin + chunk; if (end > NNODES) end = NNODES;
    if (begin > NNODES) begin = NNODES;
    int s = 0;
    for (int i = begin; i < end; ++i) s += deg[i];
    partial[tid] = s;
    __syncthreads();
    for (int o = 1; o < 256; o <<= 1) {
        int v = (tid >= o) ? partial[tid - o] : 0;
        __syncthreads();
        partial[tid] += v;
        __syncthreads();
    }
    int run = (tid > 0) ? partial[tid - 1] : 0;  // exclusive prefix
    for (int i = begin; i < end; ++i) {
        off[i] = run; cursor[i] = run; run += deg[i];
    }
    if (tid == 255) off[NNODES] = run; // == EPLUS
}

__global__ void scatter_edges(const int* __restrict__ ei, int* __restrict__ cursor,
                              int* __restrict__ csr)
{
    int e = blockIdx.x * blockDim.x + threadIdx.x;
    if (e >= EPLUS) return;
    int srcN, dstN;
    if (e < EDGES) { srcN = ei[e]; dstN = ei[EDGES + e]; }
    else           { srcN = dstN = e - EDGES; }
    int pos = atomicAdd(&cursor[dstN], 1);
    csr[pos] = srcN;
}

// ---------------------------------------------------------------------------
// fp32 -> fp16 conversions
// ---------------------------------------------------------------------------
__global__ void conv_f32_f16(const float* __restrict__ src,
                             _Float16* __restrict__ dst, int n4)
{
    int i = blockIdx.x * 256 + threadIdx.x;
    if (i >= n4) return;
    float4 v = ((const float4*)src)[i];
    f16x4 o;
    o[0] = (_Float16)v.x; o[1] = (_Float16)v.y;
    o[2] = (_Float16)v.z; o[3] = (_Float16)v.w;
    ((f16x4*)dst)[i] = o;
}

// z=0..2: W [512x512] (KxN) -> Wt [NxK] fp16.  z=3: W3 [512x64] -> W3t [64x512]
__global__ void transp4_f32_f16(const float* __restrict__ Wa,
                                const float* __restrict__ Wb,
                                const float* __restrict__ Wc,
                                const float* __restrict__ Wd,
                                _Float16* __restrict__ Ta,
                                _Float16* __restrict__ Tb,
                                _Float16* __restrict__ Tc,
                                _Float16* __restrict__ Td)
{
    const int z = blockIdx.z;
    if (z == 3 && blockIdx.x >= 2) return;   // W3 has only 64 cols
    const float* W = (z == 0) ? Wa : (z == 1) ? Wb : (z == 2) ? Wc : Wd;
    _Float16*    T = (z == 0) ? Ta : (z == 1) ? Tb : (z == 2) ? Tc : Td;
    const int ldW = (z == 3) ? 64 : 512;
    __shared__ float t[32][33];
    int bx = blockIdx.x * 32, by = blockIdx.y * 32;
    int tx = threadIdx.x, ty = threadIdx.y;   // 32 x 8
    #pragma unroll
    for (int i = 0; i < 32; i += 8)
        t[ty + i][tx] = W[(size_t)(by + ty + i) * ldW + bx + tx];
    __syncthreads();
    #pragma unroll
    for (int i = 0; i < 32; i += 8)
        T[(size_t)(bx + ty + i) * 512 + by + tx] = (_Float16)t[tx][ty + i];
}

// ---------------------------------------------------------------------------
// fp16 MFMA GEMM: C[M,N] = A16[M,K] @ Bt16[N,K]^T (+bias), 128x128 tile
// ---------------------------------------------------------------------------
__global__ __launch_bounds__(256) void gemm_f16_mfma(
    const _Float16* __restrict__ A16, const _Float16* __restrict__ Bt16,
    const float* __restrict__ bias, float* __restrict__ Cp,
    _Float16* __restrict__ C16, int M, int Nn, int K)
{
    __shared__ _Float16 As[128 * 32] __attribute__((aligned(16)));
    __shared__ _Float16 Bs[128 * 32] __attribute__((aligned(16)));
    const int tid  = threadIdx.x;
    const int wave = tid >> 6;
    const int lane = tid & 63;
    const int row0 = blockIdx.y * 128;
    const int col0 = blockIdx.x * 128;
    const int wy = wave >> 1, wx = wave & 1;

    const int lrow = lane >> 2;
    const int lk   = (lane & 3) * 8;

    f32x4 acc[4][4] = {};

    for (int k0 = 0; k0 < K; k0 += 32) {
        if (k0) __syncthreads();
        #pragma unroll
        for (int r = 0; r < 2; ++r) {
            const int chunk = r * 4 + wave;
            const int trow  = chunk * 16 + lrow;
            const _Float16* ga = A16 + (size_t)(row0 + trow) * K + k0 + lk;
            GLD_LDS16(ga, &As[chunk * 512]);
            const _Float16* gb = Bt16 + (size_t)(col0 + trow) * K + k0 + lk;
            GLD_LDS16(gb, &Bs[chunk * 512]);
        }
        __syncthreads();

        const int quad = lane >> 4;
        const int l16  = lane & 15;
        f16x8 af[4], bf[4];
        #pragma unroll
        for (int m = 0; m < 4; ++m)
            af[m] = *(const f16x8*)&As[(wy * 64 + m * 16 + l16) * 32 + quad * 8];
        #pragma unroll
        for (int n = 0; n < 4; ++n)
            bf[n] = *(const f16x8*)&Bs[(wx * 64 + n * 16 + l16) * 32 + quad * 8];
        #pragma unroll
        for (int m = 0; m < 4; ++m)
            #pragma unroll
            for (int n = 0; n < 4; ++n)
                acc[m][n] = __builtin_amdgcn_mfma_f32_16x16x32_f16(
                    af[m], bf[n], acc[m][n], 0, 0, 0);
    }

    const int quad = lane >> 4;
    const int l16  = lane & 15;
    #pragma unroll
    for (int m = 0; m < 4; ++m) {
        #pragma unroll
        for (int n = 0; n < 4; ++n) {
            const int col = col0 + wx * 64 + n * 16 + l16;
            const float bv = bias ? bias[col] : 0.0f;
            #pragma unroll
            for (int r = 0; r < 4; ++r) {
                const int row = row0 + wy * 64 + m * 16 + quad * 4 + r;
                if (row < M) {
                    float v = acc[m][n][r] + bv;
                    if (Cp)  Cp[(size_t)row * Nn + col] = v;
                    if (C16) C16[(size_t)row * Nn + col] = (_Float16)v;
                }
            }
        }
    }
}

// ---------------------------------------------------------------------------
// fp16 MFMA GEMM, N=64 (layer 3): C16[M,64] = A16[M,512] @ Bt16[64,512]^T
// 64x64 tile, 4 waves (2x2), BK=32
// ---------------------------------------------------------------------------
__global__ __launch_bounds__(256) void gemm_f16_mfma_n64(
    const _Float16* __restrict__ A16, const _Float16* __restrict__ Bt16,
    _Float16* __restrict__ C16, int M)
{
    __shared__ _Float16 As[64 * 32] __attribute__((aligned(16)));
    __shared__ _Float16 Bs[64 * 32] __attribute__((aligned(16)));
    const int tid  = threadIdx.x;
    const int wave = tid >> 6;
    const int lane = tid & 63;
    const int row0 = blockIdx.x * 64;
    const int wy = wave >> 1, wx = wave & 1;

    const int lrow = lane >> 2;
    const int lk   = (lane & 3) * 8;

    f32x4 acc[2][2] = {};

    for (int k0 = 0; k0 < 512; k0 += 32) {
        if (k0) __syncthreads();
        {
            const int trow = wave * 16 + lrow;
            GLD_LDS16(A16 + (size_t)(row0 + trow) * 512 + k0 + lk, &As[wave * 512]);
            GLD_LDS16(Bt16 + (size_t)trow * 512 + k0 + lk, &Bs[wave * 512]);
        }
        __syncthreads();

        const int quad = lane >> 4;
        const int l16  = lane & 15;
        f16x8 af[2], bf[2];
        #pragma unroll
        for (int m = 0; m < 2; ++m)
            af[m] = *(const f16x8*)&As[(wy * 32 + m * 16 + l16) * 32 + quad * 8];
        #pragma unroll
        for (int n = 0; n < 2; ++n)
            bf[n] = *(const f16x8*)&Bs[(wx * 32 + n * 16 + l16) * 32 + quad * 8];
        #pragma unroll
        for (int m = 0; m < 2; ++m)
            #pragma unroll
            for (int n = 0; n < 2; ++n)
                acc[m][n] = __builtin_amdgcn_mfma_f32_16x16x32_f16(
                    af[m], bf[n], acc[m][n], 0, 0, 0);
    }

    const int quad = lane >> 4;
    const int l16  = lane & 15;
    #pragma unroll
    for (int m = 0; m < 2; ++m)
        #pragma unroll
        for (int n = 0; n < 2; ++n) {
            const int col = wx * 32 + n * 16 + l16;
            #pragma unroll
            for (int r = 0; r < 2 * 2; ++r) {
                const int row = row0 + wy * 32 + m * 16 + quad * 4 + r;
                if (row < M)
                    C16[(size_t)row * 64 + col] = (_Float16)acc[m][n][r];
            }
        }
}

// ---------------------------------------------------------------------------
// Scores, vectorized for NH=8 fp16: lane owns channels [8l,8l+8), head=l>>3.
// ---------------------------------------------------------------------------
__global__ __launch_bounds__(256) void compute_scores8(
    const _Float16* __restrict__ Hf, const float* __restrict__ a_s,
    const float* __restrict__ a_d, float* __restrict__ ssrc,
    float* __restrict__ sdst)
{
    const int lane = threadIdx.x & 63;
    const int node = blockIdx.x * 4 + (threadIdx.x >> 6);
    const int head = lane >> 3;
    f16x8 hv = *(const f16x8*)(Hf + (size_t)node * HC + lane * 8);
    float vs = 0.f, vd = 0.f;
    #pragma unroll
    for (int c = 0; c < 8; ++c) {
        float v = (float)hv[c];
        vs = fmaf(v, a_s[lane * 8 + c], vs);
        vd = fmaf(v, a_d[lane * 8 + c], vd);
    }
    vs += __shfl_xor(vs, 1); vs += __shfl_xor(vs, 2); vs += __shfl_xor(vs, 4);
    vd += __shfl_xor(vd, 1); vd += __shfl_xor(vd, 2); vd += __shfl_xor(vd, 4);
    if ((lane & 7) == 0) {
        ssrc[node * HEADS8 + head] = vs;
        sdst[node * HEADS8 + head] = vd;
    }
}

// Generic scores (layer 3: NH=1)
template <int NH, typename TH>
__global__ __launch_bounds__(64) void compute_scores(
    const TH* __restrict__ Hf, const float* __restrict__ a_s,
    const float* __restrict__ a_d, float* __restrict__ ssrc,
    float* __restrict__ sdst)
{
    const int node = blockIdx.x;
    const int lane = threadIdx.x;
    const TH* hp = Hf + (size_t)node * (NH * 64) + lane;
    #pragma unroll
    for (int h = 0; h < NH; ++h) {
        float v  = (float)hp[h * 64];
        float vs = v * a_s[h * 64 + lane];
        float vd = v * a_d[h * 64 + lane];
        #pragma unroll
        for (int o = 32; o; o >>= 1) {
            vs += __shfl_down(vs, o);
            vd += __shfl_down(vd, o);
        }
        if (lane == 0) {
            ssrc[node * NH + h] = vs;
            sdst[node * NH + h] = vd;
        }
    }
}

// ---------------------------------------------------------------------------
// Segment-softmax aggregation, NH=8 fp16, lane owns 8 channels (f16x8 gather)
// ---------------------------------------------------------------------------
__global__ __launch_bounds__(64) void gat_aggregate8(
    const _Float16* __restrict__ Hf, const float* __restrict__ ssrc,
    const float* __restrict__ sdst, const int* __restrict__ off,
    const int* __restrict__ csr, const float* __restrict__ bias,
    float* __restrict__ out)
{
    const int n    = blockIdx.x;
    const int lane = threadIdx.x;
    const int head = lane >> 3;
    const int e0 = off[n], e1 = off[n + 1];

    float sd[8];
    #pragma unroll
    for (int h = 0; h < 8; ++h) sd[h] = sdst[n * 8 + h];

    float mx[8];
    #pragma unroll
    for (int h = 0; h < 8; ++h) mx[h] = -1e30f;
    for (int e = e0 + lane; e < e1; e += 64) {
        int s = csr[e];
        #pragma unroll
        for (int h = 0; h < 8; ++h) {
            float l = ssrc[s * 8 + h] + sd[h];
            l = (l > 0.f) ? l : 0.2f * l;
            mx[h] = fmaxf(mx[h], l);
        }
    }
    #pragma unroll
    for (int h = 0; h < 8; ++h)
        #pragma unroll
        for (int o = 1; o < 64; o <<= 1)
            mx[h] = fmaxf(mx[h], __shfl_xor(mx[h], o));

    __shared__ float exL[64 * 8];
    __shared__ int   srcL[64];
    float acc[8]  = {};
    float ssum[8] = {};
    for (int base = e0; base < e1; base += 64) {
        int cnt = e1 - base; if (cnt > 64) cnt = 64;
        if (lane < cnt) {
            int s = csr[base + lane];
            srcL[lane] = s;
            #pragma unroll
            for (int h = 0; h < 8; ++h) {
                float l = ssrc[s * 8 + h] + sd[h];
                l = (l > 0.f) ? l : 0.2f * l;
                float ex = expf(l - mx[h]);
                exL[lane * 8 + h] = ex;
                ssum[h] += ex;
            }
        }
        __syncthreads();
        for (int j = 0; j < cnt; ++j) {
            const int s = srcL[j];
            f16x8 hv = *(const f16x8*)(Hf + (size_t)s * HC + lane * 8);
            const float al = exL[j * 8 + head];
            #pragma unroll
            for (int c = 0; c < 8; ++c)
                acc[c] = fmaf(al, (float)hv[c], acc[c]);
        }
        __syncthreads();
    }
    #pragma unroll
    for (int h = 0; h < 8; ++h)
        #pragma unroll
        for (int o = 1; o < 64; o <<= 1)
            ssum[h] += __shfl_xor(ssum[h], o);

    const float inv = 1.0f / (ssum[head] + 1e-16f);
    float* op = out + (size_t)n * HC + lane * 8;
    const float* bp = bias + lane * 8;
    #pragma unroll
    for (int c = 0; c < 8; ++c)
        op[c] = acc[c] * inv + bp[c];
}

// Generic aggregate (layer 3: NH=1)
template <int NH, typename TH>
__global__ __launch_bounds__(64) void gat_aggregate(
    const TH* __restrict__ Hf, const float* __restrict__ ssrc,
    const float* __restrict__ sdst, const int* __restrict__ off,
    const int* __restrict__ csr, const float* __restrict__ bias,
    float* __restrict__ out)
{
    const int n    = blockIdx.x;
    const int lane = threadIdx.x;
    const int e0 = off[n], e1 = off[n + 1];

    float sd[NH];
    #pragma unroll
    for (int h = 0; h < NH; ++h) sd[h] = sdst[n * NH + h];

    float mx[NH];
    #pragma unroll
    for (int h = 0; h < NH; ++h) mx[h] = -1e30f;
    for (int e = e0 + lane; e < e1; e += 64) {
        int s = csr[e];
        #pragma unroll
        for (int h = 0; h < NH; ++h) {
            float l = ssrc[s * NH + h] + sd[h];
            l = (l > 0.f) ? l : 0.2f * l;
            mx[h] = fmaxf(mx[h], l);
        }
    }
    #pragma unroll
    for (int h = 0; h < NH; ++h)
        #pragma unroll
        for (int o = 1; o < 64; o <<= 1)
            mx[h] = fmaxf(mx[h], __shfl_xor(mx[h], o));

    __shared__ float exL[64][NH];
    __shared__ int   srcL[64];
    float acc[NH]  = {};
    float ssum[NH] = {};
    for (int base = e0; base < e1; base += 64) {
        int cnt = e1 - base; if (cnt > 64) cnt = 64;
        if (lane < cnt) {
            int s = csr[base + lane];
            srcL[lane] = s;
            #pragma unroll
            for (int h = 0; h < NH; ++h) {
                float l = ssrc[s * NH + h] + sd[h];
                l = (l > 0.f) ? l : 0.2f * l;
                float ex = expf(l - mx[h]);
                exL[lane][h] = ex;
                ssum[h] += ex;
            }
        }
        __syncthreads();
        for (int j = 0; j < cnt; ++j) {
            const int s = srcL[j];
            const TH* hp = Hf + (size_t)s * (NH * 64) + lane;
            #pragma unroll
            for (int h = 0; h < NH; ++h)
                acc[h] = fmaf(exL[j][h], (float)hp[h * 64], acc[h]);
        }
        __syncthreads();
    }
    #pragma unroll
    for (int h = 0; h < NH; ++h)
        #pragma unroll
        for (int o = 1; o < 64; o <<= 1)
            ssum[h] += __shfl_xor(ssum[h], o);

    #pragma unroll
    for (int h = 0; h < NH; ++h)
        out[(size_t)n * (NH * 64) + h * 64 + lane] =
            acc[h] / (ssum[h] + 1e-16f) + bias[h * 64 + lane];
}

// ---------------------------------------------------------------------------
// BatchNorm: partial column sums (no atomics)
// ---------------------------------------------------------------------------
__global__ void bn_stats_part(const float* __restrict__ x,
                              float* __restrict__ psum, float* __restrict__ psq,
                              int rows, int cols)
{
    const int c   = threadIdx.x;   // blockDim.x == cols
    const int blk = blockIdx.x;    // NPART blocks
    float s = 0.f, sq = 0.f;
    for (int r = blk; r < rows; r += NPART) {
        float v = x[(size_t)r * cols + c];
        s += v; sq += v * v;
    }
    psum[(size_t)blk * cols + c] = s;
    psq [(size_t)blk * cols + c] = sq;
}

// Fused finalize+apply: each block derives per-column scale/shift from the
// NPART partials (L2-resident), then grid-strides over rows.
// v = x*scale + shift ; optional ELU, residual, fp16 emit.
__global__ __launch_bounds__(256) void bn_apply_fused(
    float* __restrict__ x, const float* __restrict__ res,
    const float* __restrict__ psum, const float* __restrict__ psq,
    const float* __restrict__ g, const float* __restrict__ be,
    _Float16* __restrict__ out16, int rows, int cols, float invN, int do_elu)
{
    __shared__ float scale_l[HC];
    __shared__ float shift_l[HC];
    const int tid = threadIdx.x;
    for (int c = tid; c < cols; c += 256) {
        float s = 0.f, sq = 0.f;
        for (int p = 0; p < NPART; ++p) {
            s  += psum[(size_t)p * cols + c];
            sq += psq [(size_t)p * cols + c];
        }
        float mu  = s * invN;
        float var = sq * invN - mu * mu;
        float istd = 1.0f / sqrtf(var + 1e-5f);
        float sc = g[c] * istd;
        scale_l[c] = sc;
        shift_l[c] = be[c] - mu * sc;
    }
    __syncthreads();
    for (int r = blockIdx.x; r < rows; r += gridDim.x) {
        for (int c = tid; c < cols; c += 256) {
            size_t i = (size_t)r * cols + c;
            float v = x[i] * scale_l[c] + shift_l[c];
            if (do_elu) v = (v > 0.f) ? v : expm1f(v);
            if (res) v += res[i];
            x[i] = v;
            if (out16) out16[i] = (_Float16)v;
        }
    }
}

// ---------------------------------------------------------------------------
// Fused global-mean-pool + final linear (one block per graph)
// ---------------------------------------------------------------------------
__global__ __launch_bounds__(256) void pool_linear(
    const float* __restrict__ x, const int* __restrict__ goff,
    const float* __restrict__ W, const float* __restrict__ b,
    float* __restrict__ out)
{
    const int g    = blockIdx.x;
    const int lane = threadIdx.x & 63;   // channel
    const int wave = threadIdx.x >> 6;   // 0..3
    const int r0 = goff[g], r1 = goff[g + 1];
    float s = 0.f;
    for (int r = r0 + wave; r < r1; r += 4)
        s += x[(size_t)r * CH + lane];
    __shared__ float red[4][CH];
    __shared__ float mean_l[CH];
    red[wave][lane] = s;
    __syncthreads();
    if (wave == 0) {
        float tot = red[0][lane] + red[1][lane] + red[2][lane] + red[3][lane];
        float cnt = (float)(r1 - r0);
        mean_l[lane] = tot / fmaxf(cnt, 1.0f);
    }
    __syncthreads();
    if (threadIdx.x < NCLS) {
        const int j = threadIdx.x;
        float acc = b[j];
        for (int c = 0; c < CH; ++c)
            acc = fmaf(mean_l[c], W[c * NCLS + j], acc);
        out[g * NCLS + j] = acc;
    }
}

// ---------------------------------------------------------------------------
// Host launcher
// ---------------------------------------------------------------------------
extern "C" void kernel_launch(void* const* d_in, const int* in_sizes, int n_in,
                              void* d_out, int out_size, void* d_ws, size_t ws_size,
                              hipStream_t stream)
{
    const float* x_in  = (const float*)d_in[0];
    const int*   ei    = (const int*)  d_in[1];
    const int*   batch = (const int*)  d_in[2];
    const float* enc_W = (const float*)d_in[3];
    const float* enc_b = (const float*)d_in[4];
    const float* W1  = (const float*)d_in[5];
    const float* as1 = (const float*)d_in[6];
    const float* ad1 = (const float*)d_in[7];
    const float* b1  = (const float*)d_in[8];
    const float* g1  = (const float*)d_in[9];
    const float* be1 = (const float*)d_in[10];
    const float* W2  = (const float*)d_in[11];
    const float* as2 = (const float*)d_in[12];
    const float* ad2 = (const float*)d_in[13];
    const float* b2  = (const float*)d_in[14];
    const float* g2  = (const float*)d_in[15];
    const float* be2 = (const float*)d_in[16];
    const float* W3  = (const float*)d_in[17];
    const float* as3 = (const float*)d_in[18];
    const float* ad3 = (const float*)d_in[19];
    const float* b3  = (const float*)d_in[20];
    const float* g3  = (const float*)d_in[21];
    const float* be3 = (const float*)d_in[22];
    const float* linW = (const float*)d_in[23];
    const float* linb = (const float*)d_in[24];
    float* out = (float*)d_out;

    char* ws = (char*)d_ws;
    size_t off_b = 0;
    auto alloc = [&](size_t bytes) -> void* {
        void* p = ws + off_b;
        off_b = (off_b + bytes + 255) & ~(size_t)255;
        return p;
    };
    float*    xA     = (float*)alloc((size_t)NNODES * HC * 4);
    float*    xC     = (float*)alloc((size_t)NNODES * HC * 4);
    _Float16* f16A   = (_Float16*)alloc((size_t)MPAD * HC * 2);
    _Float16* f16B   = (_Float16*)alloc((size_t)MPAD * HC * 2);
    _Float16* H16    = (_Float16*)alloc((size_t)NNODES * HC * 2);
    _Float16* h3_16  = (_Float16*)alloc((size_t)NNODES * CH * 2);
    float*    g3o    = (float*)alloc((size_t)NNODES * CH * 4);
    _Float16* encWt  = (_Float16*)alloc((size_t)HC * FIN * 2);
    _Float16* W1t    = (_Float16*)alloc((size_t)HC * HC * 2);
    _Float16* W2t    = (_Float16*)alloc((size_t)HC * HC * 2);
    _Float16* W3t    = (_Float16*)alloc((size_t)CH * HC * 2);
    float* ssrc   = (float*)alloc((size_t)NNODES * HEADS8 * 4);
    float* sdst   = (float*)alloc((size_t)NNODES * HEADS8 * 4);
    int*   deg    = (int*)  alloc((size_t)NNODES * 4);
    int*   offp   = (int*)  alloc((size_t)(NNODES + 1) * 4);
    int*   cursor = (int*)  alloc((size_t)NNODES * 4);
    int*   csr    = (int*)  alloc((size_t)EPLUS * 4);
    int*   goff   = (int*)  alloc((size_t)(NG + 1) * 4);
    float* psum   = (float*)alloc((size_t)NPART * HC * 4);
    float* psq    = (float*)alloc((size_t)NPART * HC * 4);

    // ---- CSR build + graph offsets
    hipMemsetAsync(deg, 0, (size_t)NNODES * 4, stream);
    count_deg_goff<<<(EPLUS + 255) / 256, 256, 0, stream>>>(ei, deg, batch, goff);
    exscan_deg<<<1, 256, 0, stream>>>(deg, offp, cursor);
    scatter_edges<<<(EPLUS + 255) / 256, 256, 0, stream>>>(ei, cursor, csr);

    // ---- fp16 conversions (input + 4 transposed weights in one kernel)
    {
        int n4 = NNODES * FIN / 4;
        conv_f32_f16<<<(n4 + 255) / 256, 256, 0, stream>>>(x_in, f16A, n4);
        dim3 tg(16, 16, 4), tb(32, 8);
        transp4_f32_f16<<<tg, tb, 0, stream>>>(enc_W, W1, W2, W3,
                                               encWt, W1t, W2t, W3t);
    }

    const dim3 mfma_grid(HC / 128, MPAD / 128);

    // ---- Encoder: xA fp32 + f16B fp16 = x_in @ enc_W + enc_b
    gemm_f16_mfma<<<mfma_grid, 256, 0, stream>>>(f16A, encWt, enc_b, xA, f16B,
                                                 NNODES, HC, FIN);

    // ---- GAT layers 1-2
    auto run_layer = [&](const _Float16* a16, const _Float16* wt,
                         const float* res, float* gout, _Float16* out16,
                         const float* a_s, const float* a_d,
                         const float* bconv, const float* gg, const float* bb) {
        gemm_f16_mfma<<<mfma_grid, 256, 0, stream>>>(a16, wt, nullptr, nullptr,
                                                     H16, NNODES, HC, HC);
        compute_scores8<<<NNODES / 4, 256, 0, stream>>>(H16, a_s, a_d, ssrc, sdst);
        gat_aggregate8<<<NNODES, 64, 0, stream>>>(H16, ssrc, sdst, offp, csr,
                                                  bconv, gout);
        bn_stats_part<<<NPART, HC, 0, stream>>>(gout, psum, psq, NNODES, HC);
        bn_apply_fused<<<128, 256, 0, stream>>>(gout, res, psum, psq, gg, bb,
                                                out16, NNODES, HC,
                                                1.0f / NNODES, 1);
    };

    // Layer 1: A=f16B, residual xA, out xC (+f16A for layer-2 GEMM)
    run_layer(f16B, W1t, xA, xC, f16A, as1, ad1, b1, g1, be1);
    // Layer 2: A=f16A, residual xC, out xA (+f16B for layer-3 GEMM)
    run_layer(f16A, W2t, xC, xA, f16B, as2, ad2, b2, g2, be2);

    // ---- Layer 3 (heads=1, C=64): fp16 MFMA GEMM
    gemm_f16_mfma_n64<<<MPAD / 64, 256, 0, stream>>>(f16B, W3t, h3_16, NNODES);
    compute_scores<1, _Float16><<<NNODES, 64, 0, stream>>>(h3_16, as3, ad3,
                                                           ssrc, sdst);
    gat_aggregate<1, _Float16><<<NNODES, 64, 0, stream>>>(h3_16, ssrc, sdst,
                                                          offp, csr, b3, g3o);
    bn_stats_part<<<NPART, CH, 0, stream>>>(g3o, psum, psq, NNODES, CH);
    bn_apply_fused<<<128, 256, 0, stream>>>(g3o, nullptr, psum, psq, g3, be3,
                                            nullptr, NNODES, CH,
                                            1.0f / NNODES, 0);

    // ---- Fused global mean pool + final linear
    pool_linear<<<NG, 256, 0, stream>>>(g3o, goff, linW, linb, out);
}

// Round 6
// 455.901 us; speedup vs baseline: 1.4984x; 1.4984x over previous
//
#include <hip/hip_runtime.h>
#include <hip/hip_bf16.h>
#include <math.h>

// Problem constants (from reference)
#define NNODES 10000
#define MPAD   10112    // 79 * 128
#define EDGES  160000
#define EPLUS  170000   // EDGES + NNODES self-loops
#define FIN    512
#define HEADS8 8
#define CH     64
#define HC     512      // HEADS8*CH
#define NG     64       // graphs
#define NCLS   64
#define NPART  128      // bn partial blocks

typedef _Float16 f16x8 __attribute__((ext_vector_type(8)));
typedef _Float16 f16x4 __attribute__((ext_vector_type(4)));
typedef float    f32x4 __attribute__((ext_vector_type(4)));

#define GLD_LDS16(g, l)                                                        \
    __builtin_amdgcn_global_load_lds(                                          \
        (const __attribute__((address_space(1))) void*)(g),                    \
        (__attribute__((address_space(3))) void*)(l), 16, 0, 0)

// ---------------------------------------------------------------------------
// CSR build: histogram of dst (+ graph offsets fused), scan, scatter
// ---------------------------------------------------------------------------
__global__ void count_deg_goff(const int* __restrict__ ei, int* __restrict__ deg,
                               const int* __restrict__ batch, int* __restrict__ goff)
{
    int e = blockIdx.x * blockDim.x + threadIdx.x;
    if (e < NNODES) {  // graph boundary detection on sorted batch
        int b = batch[e];
        int bprev = (e == 0) ? -1 : batch[e - 1];
        for (int g = bprev + 1; g <= b; ++g) goff[g] = e;
        if (e == NNODES - 1)
            for (int g = b + 1; g <= NG; ++g) goff[g] = NNODES;
    }
    if (e >= EPLUS) return;
    int dst = (e < EDGES) ? ei[EDGES + e] : (e - EDGES);
    atomicAdd(&deg[dst], 1);
}

__global__ void exscan_deg(const int* __restrict__ deg, int* __restrict__ off,
                           int* __restrict__ cursor)
{
    __shared__ int partial[256];
    const int tid = threadIdx.x;
    const int chunk = (NNODES + 255) / 256; // 40
    int begin = tid * chunk;
    int end   = begin + chunk; if (end > NNODES) end = NNODES;
    if (begin > NNODES) begin = NNODES;
    int s = 0;
    for (int i = begin; i < end; ++i) s += deg[i];
    partial[tid] = s;
    __syncthreads();
    for (int o = 1; o < 256; o <<= 1) {
        int v = (tid >= o) ? partial[tid - o] : 0;
        __syncthreads();
        partial[tid] += v;
        __syncthreads();
    }
    int run = (tid > 0) ? partial[tid - 1] : 0;  // exclusive prefix
    for (int i = begin; i < end; ++i) {
        off[i] = run; cursor[i] = run; run += deg[i];
    }
    if (tid == 255) off[NNODES] = run; // == EPLUS
}

__global__ void scatter_edges(const int* __restrict__ ei, int* __restrict__ cursor,
                              int* __restrict__ csr)
{
    int e = blockIdx.x * blockDim.x + threadIdx.x;
    if (e >= EPLUS) return;
    int srcN, dstN;
    if (e < EDGES) { srcN = ei[e]; dstN = ei[EDGES + e]; }
    else           { srcN = dstN = e - EDGES; }
    int pos = atomicAdd(&cursor[dstN], 1);
    csr[pos] = srcN;
}

// ---------------------------------------------------------------------------
// fp32 -> fp16 conversions
// ---------------------------------------------------------------------------
__global__ void conv_f32_f16(const float* __restrict__ src,
                             _Float16* __restrict__ dst, int n4)
{
    int i = blockIdx.x * 256 + threadIdx.x;
    if (i >= n4) return;
    float4 v = ((const float4*)src)[i];
    f16x4 o;
    o[0] = (_Float16)v.x; o[1] = (_Float16)v.y;
    o[2] = (_Float16)v.z; o[3] = (_Float16)v.w;
    ((f16x4*)dst)[i] = o;
}

// z=0..2: W [512x512] (KxN) -> Wt [NxK] fp16.  z=3: W3 [512x64] -> W3t [64x512]
__global__ void transp4_f32_f16(const float* __restrict__ Wa,
                                const float* __restrict__ Wb,
                                const float* __restrict__ Wc,
                                const float* __restrict__ Wd,
                                _Float16* __restrict__ Ta,
                                _Float16* __restrict__ Tb,
                                _Float16* __restrict__ Tc,
                                _Float16* __restrict__ Td)
{
    const int z = blockIdx.z;
    if (z == 3 && blockIdx.x >= 2) return;   // W3 has only 64 cols
    const float* W = (z == 0) ? Wa : (z == 1) ? Wb : (z == 2) ? Wc : Wd;
    _Float16*    T = (z == 0) ? Ta : (z == 1) ? Tb : (z == 2) ? Tc : Td;
    const int ldW = (z == 3) ? 64 : 512;
    __shared__ float t[32][33];
    int bx = blockIdx.x * 32, by = blockIdx.y * 32;
    int tx = threadIdx.x, ty = threadIdx.y;   // 32 x 8
    #pragma unroll
    for (int i = 0; i < 32; i += 8)
        t[ty + i][tx] = W[(size_t)(by + ty + i) * ldW + bx + tx];
    __syncthreads();
    #pragma unroll
    for (int i = 0; i < 32; i += 8)
        T[(size_t)(bx + ty + i) * 512 + by + tx] = (_Float16)t[tx][ty + i];
}

// ---------------------------------------------------------------------------
// fp16 MFMA GEMM: C[M,N] = A16[M,K] @ Bt16[N,K]^T (+bias), 128x128 tile
// ---------------------------------------------------------------------------
__global__ __launch_bounds__(256) void gemm_f16_mfma(
    const _Float16* __restrict__ A16, const _Float16* __restrict__ Bt16,
    const float* __restrict__ bias, float* __restrict__ Cp,
    _Float16* __restrict__ C16, int M, int Nn, int K)
{
    __shared__ _Float16 As[128 * 32] __attribute__((aligned(16)));
    __shared__ _Float16 Bs[128 * 32] __attribute__((aligned(16)));
    const int tid  = threadIdx.x;
    const int wave = tid >> 6;
    const int lane = tid & 63;
    const int row0 = blockIdx.y * 128;
    const int col0 = blockIdx.x * 128;
    const int wy = wave >> 1, wx = wave & 1;

    const int lrow = lane >> 2;
    const int lk   = (lane & 3) * 8;

    f32x4 acc[4][4] = {};

    for (int k0 = 0; k0 < K; k0 += 32) {
        if (k0) __syncthreads();
        #pragma unroll
        for (int r = 0; r < 2; ++r) {
            const int chunk = r * 4 + wave;
            const int trow  = chunk * 16 + lrow;
            const _Float16* ga = A16 + (size_t)(row0 + trow) * K + k0 + lk;
            GLD_LDS16(ga, &As[chunk * 512]);
            const _Float16* gb = Bt16 + (size_t)(col0 + trow) * K + k0 + lk;
            GLD_LDS16(gb, &Bs[chunk * 512]);
        }
        __syncthreads();

        const int quad = lane >> 4;
        const int l16  = lane & 15;
        f16x8 af[4], bf[4];
        #pragma unroll
        for (int m = 0; m < 4; ++m)
            af[m] = *(const f16x8*)&As[(wy * 64 + m * 16 + l16) * 32 + quad * 8];
        #pragma unroll
        for (int n = 0; n < 4; ++n)
            bf[n] = *(const f16x8*)&Bs[(wx * 64 + n * 16 + l16) * 32 + quad * 8];
        #pragma unroll
        for (int m = 0; m < 4; ++m)
            #pragma unroll
            for (int n = 0; n < 4; ++n)
                acc[m][n] = __builtin_amdgcn_mfma_f32_16x16x32_f16(
                    af[m], bf[n], acc[m][n], 0, 0, 0);
    }

    const int quad = lane >> 4;
    const int l16  = lane & 15;
    #pragma unroll
    for (int m = 0; m < 4; ++m) {
        #pragma unroll
        for (int n = 0; n < 4; ++n) {
            const int col = col0 + wx * 64 + n * 16 + l16;
            const float bv = bias ? bias[col] : 0.0f;
            #pragma unroll
            for (int r = 0; r < 4; ++r) {
                const int row = row0 + wy * 64 + m * 16 + quad * 4 + r;
                if (row < M) {
                    float v = acc[m][n][r] + bv;
                    if (Cp)  Cp[(size_t)row * Nn + col] = v;
                    if (C16) C16[(size_t)row * Nn + col] = (_Float16)v;
                }
            }
        }
    }
}

// ---------------------------------------------------------------------------
// fp16 MFMA GEMM, N=64 (layer 3): C16[M,64] = A16[M,512] @ Bt16[64,512]^T
// ---------------------------------------------------------------------------
__global__ __launch_bounds__(256) void gemm_f16_mfma_n64(
    const _Float16* __restrict__ A16, const _Float16* __restrict__ Bt16,
    _Float16* __restrict__ C16, int M)
{
    __shared__ _Float16 As[64 * 32] __attribute__((aligned(16)));
    __shared__ _Float16 Bs[64 * 32] __attribute__((aligned(16)));
    const int tid  = threadIdx.x;
    const int wave = tid >> 6;
    const int lane = tid & 63;
    const int row0 = blockIdx.x * 64;
    const int wy = wave >> 1, wx = wave & 1;

    const int lrow = lane >> 2;
    const int lk   = (lane & 3) * 8;

    f32x4 acc[2][2] = {};

    for (int k0 = 0; k0 < 512; k0 += 32) {
        if (k0) __syncthreads();
        {
            const int trow = wave * 16 + lrow;
            GLD_LDS16(A16 + (size_t)(row0 + trow) * 512 + k0 + lk, &As[wave * 512]);
            GLD_LDS16(Bt16 + (size_t)trow * 512 + k0 + lk, &Bs[wave * 512]);
        }
        __syncthreads();

        const int quad = lane >> 4;
        const int l16  = lane & 15;
        f16x8 af[2], bf[2];
        #pragma unroll
        for (int m = 0; m < 2; ++m)
            af[m] = *(const f16x8*)&As[(wy * 32 + m * 16 + l16) * 32 + quad * 8];
        #pragma unroll
        for (int n = 0; n < 2; ++n)
            bf[n] = *(const f16x8*)&Bs[(wx * 32 + n * 16 + l16) * 32 + quad * 8];
        #pragma unroll
        for (int m = 0; m < 2; ++m)
            #pragma unroll
            for (int n = 0; n < 2; ++n)
                acc[m][n] = __builtin_amdgcn_mfma_f32_16x16x32_f16(
                    af[m], bf[n], acc[m][n], 0, 0, 0);
    }

    const int quad = lane >> 4;
    const int l16  = lane & 15;
    #pragma unroll
    for (int m = 0; m < 2; ++m)
        #pragma unroll
        for (int n = 0; n < 2; ++n) {
            const int col = wx * 32 + n * 16 + l16;
            #pragma unroll
            for (int r = 0; r < 4; ++r) {
                const int row = row0 + wy * 32 + m * 16 + quad * 4 + r;
                if (row < M)
                    C16[(size_t)row * 64 + col] = (_Float16)acc[m][n][r];
            }
        }
}

// ---------------------------------------------------------------------------
// Scores, vectorized for NH=8 fp16: lane owns channels [8l,8l+8), head=l>>3.
// ---------------------------------------------------------------------------
__global__ __launch_bounds__(256) void compute_scores8(
    const _Float16* __restrict__ Hf, const float* __restrict__ a_s,
    const float* __restrict__ a_d, float* __restrict__ ssrc,
    float* __restrict__ sdst)
{
    const int lane = threadIdx.x & 63;
    const int node = blockIdx.x * 4 + (threadIdx.x >> 6);
    const int head = lane >> 3;
    f16x8 hv = *(const f16x8*)(Hf + (size_t)node * HC + lane * 8);
    float vs = 0.f, vd = 0.f;
    #pragma unroll
    for (int c = 0; c < 8; ++c) {
        float v = (float)hv[c];
        vs = fmaf(v, a_s[lane * 8 + c], vs);
        vd = fmaf(v, a_d[lane * 8 + c], vd);
    }
    vs += __shfl_xor(vs, 1); vs += __shfl_xor(vs, 2); vs += __shfl_xor(vs, 4);
    vd += __shfl_xor(vd, 1); vd += __shfl_xor(vd, 2); vd += __shfl_xor(vd, 4);
    if ((lane & 7) == 0) {
        ssrc[node * HEADS8 + head] = vs;
        sdst[node * HEADS8 + head] = vd;
    }
}

// Generic scores (layer 3: NH=1)
template <int NH, typename TH>
__global__ __launch_bounds__(64) void compute_scores(
    const TH* __restrict__ Hf, const float* __restrict__ a_s,
    const float* __restrict__ a_d, float* __restrict__ ssrc,
    float* __restrict__ sdst)
{
    const int node = blockIdx.x;
    const int lane = threadIdx.x;
    const TH* hp = Hf + (size_t)node * (NH * 64) + lane;
    #pragma unroll
    for (int h = 0; h < NH; ++h) {
        float v  = (float)hp[h * 64];
        float vs = v * a_s[h * 64 + lane];
        float vd = v * a_d[h * 64 + lane];
        #pragma unroll
        for (int o = 32; o; o >>= 1) {
            vs += __shfl_down(vs, o);
            vd += __shfl_down(vd, o);
        }
        if (lane == 0) {
            ssrc[node * NH + h] = vs;
            sdst[node * NH + h] = vd;
        }
    }
}

// ---------------------------------------------------------------------------
// Segment-softmax aggregation, NH=8 fp16, lane owns 8 channels (f16x8 gather)
// Logit reads vectorized as float4 pairs.
// ---------------------------------------------------------------------------
__global__ __launch_bounds__(64) void gat_aggregate8(
    const _Float16* __restrict__ Hf, const float* __restrict__ ssrc,
    const float* __restrict__ sdst, const int* __restrict__ off,
    const int* __restrict__ csr, const float* __restrict__ bias,
    float* __restrict__ out)
{
    const int n    = blockIdx.x;
    const int lane = threadIdx.x;
    const int head = lane >> 3;
    const int e0 = off[n], e1 = off[n + 1];

    float4 sd0 = ((const float4*)(sdst + n * 8))[0];
    float4 sd1 = ((const float4*)(sdst + n * 8))[1];
    float sd[8] = {sd0.x, sd0.y, sd0.z, sd0.w, sd1.x, sd1.y, sd1.z, sd1.w};

    float mx[8];
    #pragma unroll
    for (int h = 0; h < 8; ++h) mx[h] = -1e30f;
    for (int e = e0 + lane; e < e1; e += 64) {
        int s = csr[e];
        float4 s0 = ((const float4*)(ssrc + s * 8))[0];
        float4 s1 = ((const float4*)(ssrc + s * 8))[1];
        float lv[8] = {s0.x, s0.y, s0.z, s0.w, s1.x, s1.y, s1.z, s1.w};
        #pragma unroll
        for (int h = 0; h < 8; ++h) {
            float l = lv[h] + sd[h];
            l = (l > 0.f) ? l : 0.2f * l;
            mx[h] = fmaxf(mx[h], l);
        }
    }
    #pragma unroll
    for (int h = 0; h < 8; ++h)
        #pragma unroll
        for (int o = 1; o < 64; o <<= 1)
            mx[h] = fmaxf(mx[h], __shfl_xor(mx[h], o));

    __shared__ float exL[64 * 8];
    __shared__ int   srcL[64];
    float acc[8]  = {};
    float ssum[8] = {};
    for (int base = e0; base < e1; base += 64) {
        int cnt = e1 - base; if (cnt > 64) cnt = 64;
        if (lane < cnt) {
            int s = csr[base + lane];
            srcL[lane] = s;
            float4 s0 = ((const float4*)(ssrc + s * 8))[0];
            float4 s1 = ((const float4*)(ssrc + s * 8))[1];
            float lv[8] = {s0.x, s0.y, s0.z, s0.w, s1.x, s1.y, s1.z, s1.w};
            #pragma unroll
            for (int h = 0; h < 8; ++h) {
                float l = lv[h] + sd[h];
                l = (l > 0.f) ? l : 0.2f * l;
                float ex = expf(l - mx[h]);
                exL[lane * 8 + h] = ex;
                ssum[h] += ex;
            }
        }
        __syncthreads();
        for (int j = 0; j < cnt; ++j) {
            const int s = srcL[j];
            f16x8 hv = *(const f16x8*)(Hf + (size_t)s * HC + lane * 8);
            const float al = exL[j * 8 + head];
            #pragma unroll
            for (int c = 0; c < 8; ++c)
                acc[c] = fmaf(al, (float)hv[c], acc[c]);
        }
        __syncthreads();
    }
    #pragma unroll
    for (int h = 0; h < 8; ++h)
        #pragma unroll
        for (int o = 1; o < 64; o <<= 1)
            ssum[h] += __shfl_xor(ssum[h], o);

    const float inv = 1.0f / (ssum[head] + 1e-16f);
    float* op = out + (size_t)n * HC + lane * 8;
    const float* bp = bias + lane * 8;
    #pragma unroll
    for (int c = 0; c < 8; ++c)
        op[c] = acc[c] * inv + bp[c];
}

// Generic aggregate (layer 3: NH=1)
template <int NH, typename TH>
__global__ __launch_bounds__(64) void gat_aggregate(
    const TH* __restrict__ Hf, const float* __restrict__ ssrc,
    const float* __restrict__ sdst, const int* __restrict__ off,
    const int* __restrict__ csr, const float* __restrict__ bias,
    float* __restrict__ out)
{
    const int n    = blockIdx.x;
    const int lane = threadIdx.x;
    const int e0 = off[n], e1 = off[n + 1];

    float sd[NH];
    #pragma unroll
    for (int h = 0; h < NH; ++h) sd[h] = sdst[n * NH + h];

    float mx[NH];
    #pragma unroll
    for (int h = 0; h < NH; ++h) mx[h] = -1e30f;
    for (int e = e0 + lane; e < e1; e += 64) {
        int s = csr[e];
        #pragma unroll
        for (int h = 0; h < NH; ++h) {
            float l = ssrc[s * NH + h] + sd[h];
            l = (l > 0.f) ? l : 0.2f * l;
            mx[h] = fmaxf(mx[h], l);
        }
    }
    #pragma unroll
    for (int h = 0; h < NH; ++h)
        #pragma unroll
        for (int o = 1; o < 64; o <<= 1)
            mx[h] = fmaxf(mx[h], __shfl_xor(mx[h], o));

    __shared__ float exL[64][NH];
    __shared__ int   srcL[64];
    float acc[NH]  = {};
    float ssum[NH] = {};
    for (int base = e0; base < e1; base += 64) {
        int cnt = e1 - base; if (cnt > 64) cnt = 64;
        if (lane < cnt) {
            int s = csr[base + lane];
            srcL[lane] = s;
            #pragma unroll
            for (int h = 0; h < NH; ++h) {
                float l = ssrc[s * NH + h] + sd[h];
                l = (l > 0.f) ? l : 0.2f * l;
                float ex = expf(l - mx[h]);
                exL[lane][h] = ex;
                ssum[h] += ex;
            }
        }
        __syncthreads();
        for (int j = 0; j < cnt; ++j) {
            const int s = srcL[j];
            const TH* hp = Hf + (size_t)s * (NH * 64) + lane;
            #pragma unroll
            for (int h = 0; h < NH; ++h)
                acc[h] = fmaf(exL[j][h], (float)hp[h * 64], acc[h]);
        }
        __syncthreads();
    }
    #pragma unroll
    for (int h = 0; h < NH; ++h)
        #pragma unroll
        for (int o = 1; o < 64; o <<= 1)
            ssum[h] += __shfl_xor(ssum[h], o);

    #pragma unroll
    for (int h = 0; h < NH; ++h)
        out[(size_t)n * (NH * 64) + h * 64 + lane] =
            acc[h] / (ssum[h] + 1e-16f) + bias[h * 64 + lane];
}

// ---------------------------------------------------------------------------
// BatchNorm: partial sums -> tiny finalize -> elementwise apply (high grid)
// ---------------------------------------------------------------------------
__global__ void bn_stats_part(const float* __restrict__ x,
                              float* __restrict__ psum, float* __restrict__ psq,
                              int rows, int cols)
{
    const int c   = threadIdx.x;   // blockDim.x == cols
    const int blk = blockIdx.x;    // NPART blocks
    float s = 0.f, sq = 0.f;
    for (int r = blk; r < rows; r += NPART) {
        float v = x[(size_t)r * cols + c];
        s += v; sq += v * v;
    }
    psum[(size_t)blk * cols + c] = s;
    psq [(size_t)blk * cols + c] = sq;
}

// writes per-column scale/shift:  v = x*scale + shift
__global__ void bn_finalize(const float* __restrict__ psum,
                            const float* __restrict__ psq,
                            const float* __restrict__ g, const float* __restrict__ be,
                            float* __restrict__ scale, float* __restrict__ shift,
                            int cols, float invN)
{
    int c = blockIdx.x * blockDim.x + threadIdx.x;
    if (c >= cols) return;
    float s = 0.f, sq = 0.f;
    for (int p = 0; p < NPART; ++p) {
        s  += psum[(size_t)p * cols + c];
        sq += psq [(size_t)p * cols + c];
    }
    float mu  = s * invN;
    float var = sq * invN - mu * mu;
    float istd = 1.0f / sqrtf(var + 1e-5f);
    float sc = g[c] * istd;
    scale[c] = sc;
    shift[c] = be[c] - mu * sc;
}

// elementwise: one element per thread (max grid parallelism)
__global__ void bn_apply(float* __restrict__ x, const float* __restrict__ res,
                         const float* __restrict__ scale, const float* __restrict__ shift,
                         _Float16* __restrict__ out16,
                         size_t total, int colmask, int do_elu)
{
    size_t i = (size_t)blockIdx.x * blockDim.x + threadIdx.x;
    if (i >= total) return;
    int c = (int)(i & (size_t)colmask);
    float v = x[i] * scale[c] + shift[c];
    if (do_elu) v = (v > 0.f) ? v : expm1f(v);
    if (res) v += res[i];
    x[i] = v;
    if (out16) out16[i] = (_Float16)v;
}

// ---------------------------------------------------------------------------
// Fused global-mean-pool + final linear (one block per graph)
// ---------------------------------------------------------------------------
__global__ __launch_bounds__(256) void pool_linear(
    const float* __restrict__ x, const int* __restrict__ goff,
    const float* __restrict__ W, const float* __restrict__ b,
    float* __restrict__ out)
{
    const int g    = blockIdx.x;
    const int lane = threadIdx.x & 63;   // channel
    const int wave = threadIdx.x >> 6;   // 0..3
    const int r0 = goff[g], r1 = goff[g + 1];
    float s = 0.f;
    for (int r = r0 + wave; r < r1; r += 4)
        s += x[(size_t)r * CH + lane];
    __shared__ float red[4][CH];
    __shared__ float mean_l[CH];
    red[wave][lane] = s;
    __syncthreads();
    if (wave == 0) {
        float tot = red[0][lane] + red[1][lane] + red[2][lane] + red[3][lane];
        float cnt = (float)(r1 - r0);
        mean_l[lane] = tot / fmaxf(cnt, 1.0f);
    }
    __syncthreads();
    if (threadIdx.x < NCLS) {
        const int j = threadIdx.x;
        float acc = b[j];
        for (int c = 0; c < CH; ++c)
            acc = fmaf(mean_l[c], W[c * NCLS + j], acc);
        out[g * NCLS + j] = acc;
    }
}

// ---------------------------------------------------------------------------
// Host launcher
// ---------------------------------------------------------------------------
extern "C" void kernel_launch(void* const* d_in, const int* in_sizes, int n_in,
                              void* d_out, int out_size, void* d_ws, size_t ws_size,
                              hipStream_t stream)
{
    const float* x_in  = (const float*)d_in[0];
    const int*   ei    = (const int*)  d_in[1];
    const int*   batch = (const int*)  d_in[2];
    const float* enc_W = (const float*)d_in[3];
    const float* enc_b = (const float*)d_in[4];
    const float* W1  = (const float*)d_in[5];
    const float* as1 = (const float*)d_in[6];
    const float* ad1 = (const float*)d_in[7];
    const float* b1  = (const float*)d_in[8];
    const float* g1  = (const float*)d_in[9];
    const float* be1 = (const float*)d_in[10];
    const float* W2  = (const float*)d_in[11];
    const float* as2 = (const float*)d_in[12];
    const float* ad2 = (const float*)d_in[13];
    const float* b2  = (const float*)d_in[14];
    const float* g2  = (const float*)d_in[15];
    const float* be2 = (const float*)d_in[16];
    const float* W3  = (const float*)d_in[17];
    const float* as3 = (const float*)d_in[18];
    const float* ad3 = (const float*)d_in[19];
    const float* b3  = (const float*)d_in[20];
    const float* g3  = (const float*)d_in[21];
    const float* be3 = (const float*)d_in[22];
    const float* linW = (const float*)d_in[23];
    const float* linb = (const float*)d_in[24];
    float* out = (float*)d_out;

    char* ws = (char*)d_ws;
    size_t off_b = 0;
    auto alloc = [&](size_t bytes) -> void* {
        void* p = ws + off_b;
        off_b = (off_b + bytes + 255) & ~(size_t)255;
        return p;
    };
    float*    xA     = (float*)alloc((size_t)NNODES * HC * 4);
    float*    xC     = (float*)alloc((size_t)NNODES * HC * 4);
    _Float16* f16A   = (_Float16*)alloc((size_t)MPAD * HC * 2);
    _Float16* f16B   = (_Float16*)alloc((size_t)MPAD * HC * 2);
    _Float16* H16    = (_Float16*)alloc((size_t)NNODES * HC * 2);
    _Float16* h3_16  = (_Float16*)alloc((size_t)NNODES * CH * 2);
    float*    g3o    = (float*)alloc((size_t)NNODES * CH * 4);
    _Float16* encWt  = (_Float16*)alloc((size_t)HC * FIN * 2);
    _Float16* W1t    = (_Float16*)alloc((size_t)HC * HC * 2);
    _Float16* W2t    = (_Float16*)alloc((size_t)HC * HC * 2);
    _Float16* W3t    = (_Float16*)alloc((size_t)CH * HC * 2);
    float* ssrc   = (float*)alloc((size_t)NNODES * HEADS8 * 4);
    float* sdst   = (float*)alloc((size_t)NNODES * HEADS8 * 4);
    int*   deg    = (int*)  alloc((size_t)NNODES * 4);
    int*   offp   = (int*)  alloc((size_t)(NNODES + 1) * 4);
    int*   cursor = (int*)  alloc((size_t)NNODES * 4);
    int*   csr    = (int*)  alloc((size_t)EPLUS * 4);
    int*   goff   = (int*)  alloc((size_t)(NG + 1) * 4);
    float* psum   = (float*)alloc((size_t)NPART * HC * 4);
    float* psq    = (float*)alloc((size_t)NPART * HC * 4);
    float* bnsc   = (float*)alloc(HC * 4);
    float* bnsh   = (float*)alloc(HC * 4);

    // ---- CSR build + graph offsets
    hipMemsetAsync(deg, 0, (size_t)NNODES * 4, stream);
    count_deg_goff<<<(EPLUS + 255) / 256, 256, 0, stream>>>(ei, deg, batch, goff);
    exscan_deg<<<1, 256, 0, stream>>>(deg, offp, cursor);
    scatter_edges<<<(EPLUS + 255) / 256, 256, 0, stream>>>(ei, cursor, csr);

    // ---- fp16 conversions (input + 4 transposed weights in one kernel)
    {
        int n4 = NNODES * FIN / 4;
        conv_f32_f16<<<(n4 + 255) / 256, 256, 0, stream>>>(x_in, f16A, n4);
        dim3 tg(16, 16, 4), tb(32, 8);
        transp4_f32_f16<<<tg, tb, 0, stream>>>(enc_W, W1, W2, W3,
                                               encWt, W1t, W2t, W3t);
    }

    const dim3 mfma_grid(HC / 128, MPAD / 128);

    // ---- Encoder: xA fp32 + f16B fp16 = x_in @ enc_W + enc_b
    gemm_f16_mfma<<<mfma_grid, 256, 0, stream>>>(f16A, encWt, enc_b, xA, f16B,
                                                 NNODES, HC, FIN);

    // ---- GAT layers 1-2
    auto run_layer = [&](const _Float16* a16, const _Float16* wt,
                         const float* res, float* gout, _Float16* out16,
                         const float* a_s, const float* a_d,
                         const float* bconv, const float* gg, const float* bb) {
        gemm_f16_mfma<<<mfma_grid, 256, 0, stream>>>(a16, wt, nullptr, nullptr,
                                                     H16, NNODES, HC, HC);
        compute_scores8<<<NNODES / 4, 256, 0, stream>>>(H16, a_s, a_d, ssrc, sdst);
        gat_aggregate8<<<NNODES, 64, 0, stream>>>(H16, ssrc, sdst, offp, csr,
                                                  bconv, gout);
        bn_stats_part<<<NPART, HC, 0, stream>>>(gout, psum, psq, NNODES, HC);
        bn_finalize<<<2, 256, 0, stream>>>(psum, psq, gg, bb, bnsc, bnsh, HC,
                                           1.0f / NNODES);
        size_t total = (size_t)NNODES * HC;
        bn_apply<<<(int)((total + 255) / 256), 256, 0, stream>>>(
            gout, res, bnsc, bnsh, out16, total, HC - 1, 1);
    };

    // Layer 1: A=f16B, residual xA, out xC (+f16A for layer-2 GEMM)
    run_layer(f16B, W1t, xA, xC, f16A, as1, ad1, b1, g1, be1);
    // Layer 2: A=f16A, residual xC, out xA (+f16B for layer-3 GEMM)
    run_layer(f16A, W2t, xC, xA, f16B, as2, ad2, b2, g2, be2);

    // ---- Layer 3 (heads=1, C=64): fp16 MFMA GEMM
    gemm_f16_mfma_n64<<<MPAD / 64, 256, 0, stream>>>(f16B, W3t, h3_16, NNODES);
    compute_scores<1, _Float16><<<NNODES, 64, 0, stream>>>(h3_16, as3, ad3,
                                                           ssrc, sdst);
    gat_aggregate<1, _Float16><<<NNODES, 64, 0, stream>>>(h3_16, ssrc, sdst,
                                                          offp, csr, b3, g3o);
    bn_stats_part<<<NPART, CH, 0, stream>>>(g3o, psum, psq, NNODES, CH);
    bn_finalize<<<1, 64, 0, stream>>>(psum, psq, g3, be3, bnsc, bnsh, CH,
                                      1.0f / NNODES);
    {
        size_t total = (size_t)NNODES * CH;
        bn_apply<<<(int)((total + 255) / 256), 256, 0, stream>>>(
            g3o, nullptr, bnsc, bnsh, nullptr, total, CH - 1, 0);
    }

    // ---- Fused global mean pool + final linear
    pool_linear<<<NG, 256, 0, stream>>>(g3o, goff, linW, linb, out);
}

// Round 7
// 436.840 us; speedup vs baseline: 1.5638x; 1.0436x over previous
//
#include <hip/hip_runtime.h>
#include <hip/hip_bf16.h>
#include <math.h>

// Problem constants (from reference)
#define NNODES 10000
#define MPAD   10112    // 79 * 128
#define EDGES  160000
#define EPLUS  170000   // EDGES + NNODES self-loops
#define FIN    512
#define HEADS8 8
#define CH     64
#define HC     512      // HEADS8*CH
#define NG     64       // graphs
#define NCLS   64
#define NPART  128      // bn partial blocks

typedef _Float16 f16x8 __attribute__((ext_vector_type(8)));
typedef _Float16 f16x4 __attribute__((ext_vector_type(4)));
typedef float    f32x4 __attribute__((ext_vector_type(4)));

#define GLD_LDS16(g, l)                                                        \
    __builtin_amdgcn_global_load_lds(                                          \
        (const __attribute__((address_space(1))) void*)(g),                    \
        (__attribute__((address_space(3))) void*)(l), 16, 0, 0)

// ---------------------------------------------------------------------------
// CSR build: histogram of dst (+ graph offsets fused), scan, scatter
// ---------------------------------------------------------------------------
__global__ void count_deg_goff(const int* __restrict__ ei, int* __restrict__ deg,
                               const int* __restrict__ batch, int* __restrict__ goff)
{
    int e = blockIdx.x * blockDim.x + threadIdx.x;
    if (e < NNODES) {  // graph boundary detection on sorted batch
        int b = batch[e];
        int bprev = (e == 0) ? -1 : batch[e - 1];
        for (int g = bprev + 1; g <= b; ++g) goff[g] = e;
        if (e == NNODES - 1)
            for (int g = b + 1; g <= NG; ++g) goff[g] = NNODES;
    }
    if (e >= EPLUS) return;
    int dst = (e < EDGES) ? ei[EDGES + e] : (e - EDGES);
    atomicAdd(&deg[dst], 1);
}

__global__ void exscan_deg(const int* __restrict__ deg, int* __restrict__ off,
                           int* __restrict__ cursor)
{
    __shared__ int partial[256];
    const int tid = threadIdx.x;
    const int chunk = (NNODES + 255) / 256; // 40
    int begin = tid * chunk;
    int end   = begin + chunk; if (end > NNODES) end = NNODES;
    if (begin > NNODES) begin = NNODES;
    int s = 0;
    for (int i = begin; i < end; ++i) s += deg[i];
    partial[tid] = s;
    __syncthreads();
    for (int o = 1; o < 256; o <<= 1) {
        int v = (tid >= o) ? partial[tid - o] : 0;
        __syncthreads();
        partial[tid] += v;
        __syncthreads();
    }
    int run = (tid > 0) ? partial[tid - 1] : 0;  // exclusive prefix
    for (int i = begin; i < end; ++i) {
        off[i] = run; cursor[i] = run; run += deg[i];
    }
    if (tid == 255) off[NNODES] = run; // == EPLUS
}

__global__ void scatter_edges(const int* __restrict__ ei, int* __restrict__ cursor,
                              int* __restrict__ csr)
{
    int e = blockIdx.x * blockDim.x + threadIdx.x;
    if (e >= EPLUS) return;
    int srcN, dstN;
    if (e < EDGES) { srcN = ei[e]; dstN = ei[EDGES + e]; }
    else           { srcN = dstN = e - EDGES; }
    int pos = atomicAdd(&cursor[dstN], 1);
    csr[pos] = srcN;
}

// ---------------------------------------------------------------------------
// fp32 -> fp16 conversions
// ---------------------------------------------------------------------------
__global__ void conv_f32_f16(const float* __restrict__ src,
                             _Float16* __restrict__ dst, int n4)
{
    int i = blockIdx.x * 256 + threadIdx.x;
    if (i >= n4) return;
    float4 v = ((const float4*)src)[i];
    f16x4 o;
    o[0] = (_Float16)v.x; o[1] = (_Float16)v.y;
    o[2] = (_Float16)v.z; o[3] = (_Float16)v.w;
    ((f16x4*)dst)[i] = o;
}

// z=0..2: W [512x512] (KxN) -> Wt [NxK] fp16.  z=3: W3 [512x64] -> W3t [64x512]
__global__ void transp4_f32_f16(const float* __restrict__ Wa,
                                const float* __restrict__ Wb,
                                const float* __restrict__ Wc,
                                const float* __restrict__ Wd,
                                _Float16* __restrict__ Ta,
                                _Float16* __restrict__ Tb,
                                _Float16* __restrict__ Tc,
                                _Float16* __restrict__ Td)
{
    const int z = blockIdx.z;
    if (z == 3 && blockIdx.x >= 2) return;   // W3 has only 64 cols
    const float* W = (z == 0) ? Wa : (z == 1) ? Wb : (z == 2) ? Wc : Wd;
    _Float16*    T = (z == 0) ? Ta : (z == 1) ? Tb : (z == 2) ? Tc : Td;
    const int ldW = (z == 3) ? 64 : 512;
    __shared__ float t[32][33];
    int bx = blockIdx.x * 32, by = blockIdx.y * 32;
    int tx = threadIdx.x, ty = threadIdx.y;   // 32 x 8
    #pragma unroll
    for (int i = 0; i < 32; i += 8)
        t[ty + i][tx] = W[(size_t)(by + ty + i) * ldW + bx + tx];
    __syncthreads();
    #pragma unroll
    for (int i = 0; i < 32; i += 8)
        T[(size_t)(bx + ty + i) * 512 + by + tx] = (_Float16)t[tx][ty + i];
}

// ---------------------------------------------------------------------------
// fp16 MFMA GEMM: C[M,N] = A16[M,K] @ Bt16[N,K]^T (+bias), 128x64 tile.
// 4 waves in 2x2; each wave 64x32 (4x2 MFMAs). BK=32. 632 blocks at N=512.
// ---------------------------------------------------------------------------
__global__ __launch_bounds__(256) void gemm_f16_mfma(
    const _Float16* __restrict__ A16, const _Float16* __restrict__ Bt16,
    const float* __restrict__ bias, float* __restrict__ Cp,
    _Float16* __restrict__ C16, int M, int Nn, int K)
{
    __shared__ _Float16 As[128 * 32] __attribute__((aligned(16)));
    __shared__ _Float16 Bs[64 * 32]  __attribute__((aligned(16)));
    const int tid  = threadIdx.x;
    const int wave = tid >> 6;
    const int lane = tid & 63;
    const int row0 = blockIdx.y * 128;
    const int col0 = blockIdx.x * 64;
    const int wy = wave >> 1, wx = wave & 1;

    const int lrow = lane >> 2;
    const int lk   = (lane & 3) * 8;

    f32x4 acc[4][2] = {};

    for (int k0 = 0; k0 < K; k0 += 32) {
        if (k0) __syncthreads();
        #pragma unroll
        for (int r = 0; r < 2; ++r) {
            const int chunk = r * 4 + wave;
            const int trow  = chunk * 16 + lrow;
            GLD_LDS16(A16 + (size_t)(row0 + trow) * K + k0 + lk,
                      &As[chunk * 512]);
        }
        {
            const int trow = wave * 16 + lrow;
            GLD_LDS16(Bt16 + (size_t)(col0 + trow) * K + k0 + lk,
                      &Bs[wave * 512]);
        }
        __syncthreads();

        const int quad = lane >> 4;
        const int l16  = lane & 15;
        f16x8 af[4], bf[2];
        #pragma unroll
        for (int m = 0; m < 4; ++m)
            af[m] = *(const f16x8*)&As[(wy * 64 + m * 16 + l16) * 32 + quad * 8];
        #pragma unroll
        for (int n = 0; n < 2; ++n)
            bf[n] = *(const f16x8*)&Bs[(wx * 32 + n * 16 + l16) * 32 + quad * 8];
        #pragma unroll
        for (int m = 0; m < 4; ++m)
            #pragma unroll
            for (int n = 0; n < 2; ++n)
                acc[m][n] = __builtin_amdgcn_mfma_f32_16x16x32_f16(
                    af[m], bf[n], acc[m][n], 0, 0, 0);
    }

    const int quad = lane >> 4;
    const int l16  = lane & 15;
    #pragma unroll
    for (int m = 0; m < 4; ++m) {
        #pragma unroll
        for (int n = 0; n < 2; ++n) {
            const int col = col0 + wx * 32 + n * 16 + l16;
            const float bv = bias ? bias[col] : 0.0f;
            #pragma unroll
            for (int r = 0; r < 4; ++r) {
                const int row = row0 + wy * 64 + m * 16 + quad * 4 + r;
                if (row < M) {
                    float v = acc[m][n][r] + bv;
                    if (Cp)  Cp[(size_t)row * Nn + col] = v;
                    if (C16) C16[(size_t)row * Nn + col] = (_Float16)v;
                }
            }
        }
    }
}

// ---------------------------------------------------------------------------
// fp16 MFMA GEMM, N=64 (layer 3): C16[M,64] = A16[M,512] @ Bt16[64,512]^T
// ---------------------------------------------------------------------------
__global__ __launch_bounds__(256) void gemm_f16_mfma_n64(
    const _Float16* __restrict__ A16, const _Float16* __restrict__ Bt16,
    _Float16* __restrict__ C16, int M)
{
    __shared__ _Float16 As[64 * 32] __attribute__((aligned(16)));
    __shared__ _Float16 Bs[64 * 32] __attribute__((aligned(16)));
    const int tid  = threadIdx.x;
    const int wave = tid >> 6;
    const int lane = tid & 63;
    const int row0 = blockIdx.x * 64;
    const int wy = wave >> 1, wx = wave & 1;

    const int lrow = lane >> 2;
    const int lk   = (lane & 3) * 8;

    f32x4 acc[2][2] = {};

    for (int k0 = 0; k0 < 512; k0 += 32) {
        if (k0) __syncthreads();
        {
            const int trow = wave * 16 + lrow;
            GLD_LDS16(A16 + (size_t)(row0 + trow) * 512 + k0 + lk, &As[wave * 512]);
            GLD_LDS16(Bt16 + (size_t)trow * 512 + k0 + lk, &Bs[wave * 512]);
        }
        __syncthreads();

        const int quad = lane >> 4;
        const int l16  = lane & 15;
        f16x8 af[2], bf[2];
        #pragma unroll
        for (int m = 0; m < 2; ++m)
            af[m] = *(const f16x8*)&As[(wy * 32 + m * 16 + l16) * 32 + quad * 8];
        #pragma unroll
        for (int n = 0; n < 2; ++n)
            bf[n] = *(const f16x8*)&Bs[(wx * 32 + n * 16 + l16) * 32 + quad * 8];
        #pragma unroll
        for (int m = 0; m < 2; ++m)
            #pragma unroll
            for (int n = 0; n < 2; ++n)
                acc[m][n] = __builtin_amdgcn_mfma_f32_16x16x32_f16(
                    af[m], bf[n], acc[m][n], 0, 0, 0);
    }

    const int quad = lane >> 4;
    const int l16  = lane & 15;
    #pragma unroll
    for (int m = 0; m < 2; ++m)
        #pragma unroll
        for (int n = 0; n < 2; ++n) {
            const int col = wx * 32 + n * 16 + l16;
            #pragma unroll
            for (int r = 0; r < 4; ++r) {
                const int row = row0 + wy * 32 + m * 16 + quad * 4 + r;
                if (row < M)
                    C16[(size_t)row * 64 + col] = (_Float16)acc[m][n][r];
            }
        }
}

// ---------------------------------------------------------------------------
// Scores, vectorized for NH=8 fp16: lane owns channels [8l,8l+8), head=l>>3.
// ---------------------------------------------------------------------------
__global__ __launch_bounds__(256) void compute_scores8(
    const _Float16* __restrict__ Hf, const float* __restrict__ a_s,
    const float* __restrict__ a_d, float* __restrict__ ssrc,
    float* __restrict__ sdst)
{
    const int lane = threadIdx.x & 63;
    const int node = blockIdx.x * 4 + (threadIdx.x >> 6);
    const int head = lane >> 3;
    f16x8 hv = *(const f16x8*)(Hf + (size_t)node * HC + lane * 8);
    float vs = 0.f, vd = 0.f;
    #pragma unroll
    for (int c = 0; c < 8; ++c) {
        float v = (float)hv[c];
        vs = fmaf(v, a_s[lane * 8 + c], vs);
        vd = fmaf(v, a_d[lane * 8 + c], vd);
    }
    vs += __shfl_xor(vs, 1); vs += __shfl_xor(vs, 2); vs += __shfl_xor(vs, 4);
    vd += __shfl_xor(vd, 1); vd += __shfl_xor(vd, 2); vd += __shfl_xor(vd, 4);
    if ((lane & 7) == 0) {
        ssrc[node * HEADS8 + head] = vs;
        sdst[node * HEADS8 + head] = vd;
    }
}

// Scores, NH=1 fp16 (layer 3)
template <int NH, typename TH>
__global__ __launch_bounds__(64) void compute_scores(
    const TH* __restrict__ Hf, const float* __restrict__ a_s,
    const float* __restrict__ a_d, float* __restrict__ ssrc,
    float* __restrict__ sdst)
{
    const int node = blockIdx.x;
    const int lane = threadIdx.x;
    const TH* hp = Hf + (size_t)node * (NH * 64) + lane;
    #pragma unroll
    for (int h = 0; h < NH; ++h) {
        float v  = (float)hp[h * 64];
        float vs = v * a_s[h * 64 + lane];
        float vd = v * a_d[h * 64 + lane];
        #pragma unroll
        for (int o = 32; o; o >>= 1) {
            vs += __shfl_down(vs, o);
            vd += __shfl_down(vd, o);
        }
        if (lane == 0) {
            ssrc[node * NH + h] = vs;
            sdst[node * NH + h] = vd;
        }
    }
}

// ---------------------------------------------------------------------------
// Segment-softmax aggregation, NH=8 fp16, SINGLE PASS (no max subtraction:
// logits are O(4) -- exp() is safe in fp32; softmax is shift-invariant so
// result is mathematically identical to the max-subtracted reference).
// lane owns channels [8l, 8l+8) (f16x8 gather), head = l>>3.
// ---------------------------------------------------------------------------
__global__ __launch_bounds__(64) void gat_aggregate8(
    const _Float16* __restrict__ Hf, const float* __restrict__ ssrc,
    const float* __restrict__ sdst, const int* __restrict__ off,
    const int* __restrict__ csr, const float* __restrict__ bias,
    float* __restrict__ out)
{
    const int n    = blockIdx.x;
    const int lane = threadIdx.x;
    const int head = lane >> 3;
    const int e0 = off[n], e1 = off[n + 1];

    float4 sd0 = ((const float4*)(sdst + n * 8))[0];
    float4 sd1 = ((const float4*)(sdst + n * 8))[1];
    float sd[8] = {sd0.x, sd0.y, sd0.z, sd0.w, sd1.x, sd1.y, sd1.z, sd1.w};

    __shared__ float exL[64 * 8];
    __shared__ int   srcL[64];
    float acc[8]  = {};
    float ssum[8] = {};
    for (int base = e0; base < e1; base += 64) {
        int cnt = e1 - base; if (cnt > 64) cnt = 64;
        if (lane < cnt) {
            int s = csr[base + lane];
            srcL[lane] = s;
            float4 s0 = ((const float4*)(ssrc + s * 8))[0];
            float4 s1 = ((const float4*)(ssrc + s * 8))[1];
            float lv[8] = {s0.x, s0.y, s0.z, s0.w, s1.x, s1.y, s1.z, s1.w};
            #pragma unroll
            for (int h = 0; h < 8; ++h) {
                float l = lv[h] + sd[h];
                l = (l > 0.f) ? l : 0.2f * l;
                float ex = expf(l);
                exL[lane * 8 + h] = ex;
                ssum[h] += ex;
            }
        }
        __syncthreads();
        for (int j = 0; j < cnt; ++j) {
            const int s = srcL[j];
            f16x8 hv = *(const f16x8*)(Hf + (size_t)s * HC + lane * 8);
            const float al = exL[j * 8 + head];
            #pragma unroll
            for (int c = 0; c < 8; ++c)
                acc[c] = fmaf(al, (float)hv[c], acc[c]);
        }
        __syncthreads();
    }
    #pragma unroll
    for (int h = 0; h < 8; ++h)
        #pragma unroll
        for (int o = 1; o < 64; o <<= 1)
            ssum[h] += __shfl_xor(ssum[h], o);

    const float inv = 1.0f / (ssum[head] + 1e-16f);
    float* op = out + (size_t)n * HC + lane * 8;
    const float* bp = bias + lane * 8;
    #pragma unroll
    for (int c = 0; c < 8; ++c)
        op[c] = acc[c] * inv + bp[c];
}

// NH=1 fp16 aggregate (layer 3), single pass, lane = channel
__global__ __launch_bounds__(64) void gat_aggregate1(
    const _Float16* __restrict__ Hf, const float* __restrict__ ssrc,
    const float* __restrict__ sdst, const int* __restrict__ off,
    const int* __restrict__ csr, const float* __restrict__ bias,
    float* __restrict__ out)
{
    const int n    = blockIdx.x;
    const int lane = threadIdx.x;
    const int e0 = off[n], e1 = off[n + 1];
    const float sd = sdst[n];

    __shared__ float exL[64];
    __shared__ int   srcL[64];
    float acc = 0.f, ssum = 0.f;
    for (int base = e0; base < e1; base += 64) {
        int cnt = e1 - base; if (cnt > 64) cnt = 64;
        if (lane < cnt) {
            int s = csr[base + lane];
            srcL[lane] = s;
            float l = ssrc[s] + sd;
            l = (l > 0.f) ? l : 0.2f * l;
            float ex = expf(l);
            exL[lane] = ex;
            ssum += ex;
        }
        __syncthreads();
        for (int j = 0; j < cnt; ++j)
            acc = fmaf(exL[j], (float)Hf[(size_t)srcL[j] * 64 + lane], acc);
        __syncthreads();
    }
    #pragma unroll
    for (int o = 1; o < 64; o <<= 1)
        ssum += __shfl_xor(ssum, o);

    out[(size_t)n * 64 + lane] = acc / (ssum + 1e-16f) + bias[lane];
}

// ---------------------------------------------------------------------------
// BatchNorm: partial sums -> tiny finalize -> vectorized elementwise apply
// ---------------------------------------------------------------------------
__global__ void bn_stats_part(const float* __restrict__ x,
                              float* __restrict__ psum, float* __restrict__ psq,
                              int rows, int cols)
{
    const int c   = threadIdx.x;   // blockDim.x == cols
    const int blk = blockIdx.x;    // NPART blocks
    float s = 0.f, sq = 0.f;
    for (int r = blk; r < rows; r += NPART) {
        float v = x[(size_t)r * cols + c];
        s += v; sq += v * v;
    }
    psum[(size_t)blk * cols + c] = s;
    psq [(size_t)blk * cols + c] = sq;
}

__global__ void bn_finalize(const float* __restrict__ psum,
                            const float* __restrict__ psq,
                            const float* __restrict__ g, const float* __restrict__ be,
                            float* __restrict__ scale, float* __restrict__ shift,
                            int cols, float invN)
{
    int c = blockIdx.x * blockDim.x + threadIdx.x;
    if (c >= cols) return;
    float s = 0.f, sq = 0.f;
    for (int p = 0; p < NPART; ++p) {
        s  += psum[(size_t)p * cols + c];
        sq += psq [(size_t)p * cols + c];
    }
    float mu  = s * invN;
    float var = sq * invN - mu * mu;
    float istd = 1.0f / sqrtf(var + 1e-5f);
    float sc = g[c] * istd;
    scale[c] = sc;
    shift[c] = be[c] - mu * sc;
}

// vectorized apply: 4 consecutive elements (same 4-col group) per thread
__global__ void bn_apply(float* __restrict__ x, const float* __restrict__ res,
                         const float* __restrict__ scale, const float* __restrict__ shift,
                         _Float16* __restrict__ out16,
                         size_t total4, int colmask, int do_elu)
{
    size_t i = (size_t)blockIdx.x * blockDim.x + threadIdx.x;
    if (i >= total4) return;
    int c = (int)((i * 4) & (size_t)colmask);
    float4 xv = ((const float4*)x)[i];
    float4 sc = *(const float4*)(scale + c);
    float4 sh = *(const float4*)(shift + c);
    float v0 = xv.x * sc.x + sh.x;
    float v1 = xv.y * sc.y + sh.y;
    float v2 = xv.z * sc.z + sh.z;
    float v3 = xv.w * sc.w + sh.w;
    if (do_elu) {
        v0 = (v0 > 0.f) ? v0 : expm1f(v0);
        v1 = (v1 > 0.f) ? v1 : expm1f(v1);
        v2 = (v2 > 0.f) ? v2 : expm1f(v2);
        v3 = (v3 > 0.f) ? v3 : expm1f(v3);
    }
    if (res) {
        float4 rv = ((const float4*)res)[i];
        v0 += rv.x; v1 += rv.y; v2 += rv.z; v3 += rv.w;
    }
    ((float4*)x)[i] = make_float4(v0, v1, v2, v3);
    if (out16) {
        f16x4 o;
        o[0] = (_Float16)v0; o[1] = (_Float16)v1;
        o[2] = (_Float16)v2; o[3] = (_Float16)v3;
        ((f16x4*)out16)[i] = o;
    }
}

// ---------------------------------------------------------------------------
// Fused global-mean-pool + final linear (one block per graph)
// ---------------------------------------------------------------------------
__global__ __launch_bounds__(256) void pool_linear(
    const float* __restrict__ x, const int* __restrict__ goff,
    const float* __restrict__ W, const float* __restrict__ b,
    float* __restrict__ out)
{
    const int g    = blockIdx.x;
    const int lane = threadIdx.x & 63;   // channel
    const int wave = threadIdx.x >> 6;   // 0..3
    const int r0 = goff[g], r1 = goff[g + 1];
    float s = 0.f;
    for (int r = r0 + wave; r < r1; r += 4)
        s += x[(size_t)r * CH + lane];
    __shared__ float red[4][CH];
    __shared__ float mean_l[CH];
    red[wave][lane] = s;
    __syncthreads();
    if (wave == 0) {
        float tot = red[0][lane] + red[1][lane] + red[2][lane] + red[3][lane];
        float cnt = (float)(r1 - r0);
        mean_l[lane] = tot / fmaxf(cnt, 1.0f);
    }
    __syncthreads();
    if (threadIdx.x < NCLS) {
        const int j = threadIdx.x;
        float acc = b[j];
        for (int c = 0; c < CH; ++c)
            acc = fmaf(mean_l[c], W[c * NCLS + j], acc);
        out[g * NCLS + j] = acc;
    }
}

// ---------------------------------------------------------------------------
// Host launcher
// ---------------------------------------------------------------------------
extern "C" void kernel_launch(void* const* d_in, const int* in_sizes, int n_in,
                              void* d_out, int out_size, void* d_ws, size_t ws_size,
                              hipStream_t stream)
{
    const float* x_in  = (const float*)d_in[0];
    const int*   ei    = (const int*)  d_in[1];
    const int*   batch = (const int*)  d_in[2];
    const float* enc_W = (const float*)d_in[3];
    const float* enc_b = (const float*)d_in[4];
    const float* W1  = (const float*)d_in[5];
    const float* as1 = (const float*)d_in[6];
    const float* ad1 = (const float*)d_in[7];
    const float* b1  = (const float*)d_in[8];
    const float* g1  = (const float*)d_in[9];
    const float* be1 = (const float*)d_in[10];
    const float* W2  = (const float*)d_in[11];
    const float* as2 = (const float*)d_in[12];
    const float* ad2 = (const float*)d_in[13];
    const float* b2  = (const float*)d_in[14];
    const float* g2  = (const float*)d_in[15];
    const float* be2 = (const float*)d_in[16];
    const float* W3  = (const float*)d_in[17];
    const float* as3 = (const float*)d_in[18];
    const float* ad3 = (const float*)d_in[19];
    const float* b3  = (const float*)d_in[20];
    const float* g3  = (const float*)d_in[21];
    const float* be3 = (const float*)d_in[22];
    const float* linW = (const float*)d_in[23];
    const float* linb = (const float*)d_in[24];
    float* out = (float*)d_out;

    char* ws = (char*)d_ws;
    size_t off_b = 0;
    auto alloc = [&](size_t bytes) -> void* {
        void* p = ws + off_b;
        off_b = (off_b + bytes + 255) & ~(size_t)255;
        return p;
    };
    float*    xA     = (float*)alloc((size_t)NNODES * HC * 4);
    float*    xC     = (float*)alloc((size_t)NNODES * HC * 4);
    _Float16* f16A   = (_Float16*)alloc((size_t)MPAD * HC * 2);
    _Float16* f16B   = (_Float16*)alloc((size_t)MPAD * HC * 2);
    _Float16* H16    = (_Float16*)alloc((size_t)NNODES * HC * 2);
    _Float16* h3_16  = (_Float16*)alloc((size_t)NNODES * CH * 2);
    float*    g3o    = (float*)alloc((size_t)NNODES * CH * 4);
    _Float16* encWt  = (_Float16*)alloc((size_t)HC * FIN * 2);
    _Float16* W1t    = (_Float16*)alloc((size_t)HC * HC * 2);
    _Float16* W2t    = (_Float16*)alloc((size_t)HC * HC * 2);
    _Float16* W3t    = (_Float16*)alloc((size_t)CH * HC * 2);
    float* ssrc   = (float*)alloc((size_t)NNODES * HEADS8 * 4);
    float* sdst   = (float*)alloc((size_t)NNODES * HEADS8 * 4);
    int*   deg    = (int*)  alloc((size_t)NNODES * 4);
    int*   offp   = (int*)  alloc((size_t)(NNODES + 1) * 4);
    int*   cursor = (int*)  alloc((size_t)NNODES * 4);
    int*   csr    = (int*)  alloc((size_t)EPLUS * 4);
    int*   goff   = (int*)  alloc((size_t)(NG + 1) * 4);
    float* psum   = (float*)alloc((size_t)NPART * HC * 4);
    float* psq    = (float*)alloc((size_t)NPART * HC * 4);
    float* bnsc   = (float*)alloc(HC * 4);
    float* bnsh   = (float*)alloc(HC * 4);

    // ---- CSR build + graph offsets
    hipMemsetAsync(deg, 0, (size_t)NNODES * 4, stream);
    count_deg_goff<<<(EPLUS + 255) / 256, 256, 0, stream>>>(ei, deg, batch, goff);
    exscan_deg<<<1, 256, 0, stream>>>(deg, offp, cursor);
    scatter_edges<<<(EPLUS + 255) / 256, 256, 0, stream>>>(ei, cursor, csr);

    // ---- fp16 conversions (input + 4 transposed weights in one kernel)
    {
        int n4 = NNODES * FIN / 4;
        conv_f32_f16<<<(n4 + 255) / 256, 256, 0, stream>>>(x_in, f16A, n4);
        dim3 tg(16, 16, 4), tb(32, 8);
        transp4_f32_f16<<<tg, tb, 0, stream>>>(enc_W, W1, W2, W3,
                                               encWt, W1t, W2t, W3t);
    }

    const dim3 mfma_grid(HC / 64, MPAD / 128);   // (8, 79) = 632 blocks

    // ---- Encoder: xA fp32 + f16B fp16 = x_in @ enc_W + enc_b
    gemm_f16_mfma<<<mfma_grid, 256, 0, stream>>>(f16A, encWt, enc_b, xA, f16B,
                                                 NNODES, HC, FIN);

    // ---- GAT layers 1-2
    auto run_layer = [&](const _Float16* a16, const _Float16* wt,
                         const float* res, float* gout, _Float16* out16,
                         const float* a_s, const float* a_d,
                         const float* bconv, const float* gg, const float* bb) {
        gemm_f16_mfma<<<mfma_grid, 256, 0, stream>>>(a16, wt, nullptr, nullptr,
                                                     H16, NNODES, HC, HC);
        compute_scores8<<<NNODES / 4, 256, 0, stream>>>(H16, a_s, a_d, ssrc, sdst);
        gat_aggregate8<<<NNODES, 64, 0, stream>>>(H16, ssrc, sdst, offp, csr,
                                                  bconv, gout);
        bn_stats_part<<<NPART, HC, 0, stream>>>(gout, psum, psq, NNODES, HC);
        bn_finalize<<<2, 256, 0, stream>>>(psum, psq, gg, bb, bnsc, bnsh, HC,
                                           1.0f / NNODES);
        size_t total4 = (size_t)NNODES * HC / 4;
        bn_apply<<<(int)((total4 + 255) / 256), 256, 0, stream>>>(
            gout, res, bnsc, bnsh, out16, total4, HC - 1, 1);
    };

    // Layer 1: A=f16B, residual xA, out xC (+f16A for layer-2 GEMM)
    run_layer(f16B, W1t, xA, xC, f16A, as1, ad1, b1, g1, be1);
    // Layer 2: A=f16A, residual xC, out xA (+f16B for layer-3 GEMM)
    run_layer(f16A, W2t, xC, xA, f16B, as2, ad2, b2, g2, be2);

    // ---- Layer 3 (heads=1, C=64): fp16 MFMA GEMM
    gemm_f16_mfma_n64<<<MPAD / 64, 256, 0, stream>>>(f16B, W3t, h3_16, NNODES);
    compute_scores<1, _Float16><<<NNODES, 64, 0, stream>>>(h3_16, as3, ad3,
                                                           ssrc, sdst);
    gat_aggregate1<<<NNODES, 64, 0, stream>>>(h3_16, ssrc, sdst, offp, csr,
                                              b3, g3o);
    bn_stats_part<<<NPART, CH, 0, stream>>>(g3o, psum, psq, NNODES, CH);
    bn_finalize<<<1, 64, 0, stream>>>(psum, psq, g3, be3, bnsc, bnsh, CH,
                                      1.0f / NNODES);
    {
        size_t total4 = (size_t)NNODES * CH / 4;
        bn_apply<<<(int)((total4 + 255) / 256), 256, 0, stream>>>(
            g3o, nullptr, bnsc, bnsh, nullptr, total4, CH - 1, 0);
    }

    // ---- Fused global mean pool + final linear
    pool_linear<<<NG, 256, 0, stream>>>(g3o, goff, linW, linb, out);
}

// Round 8
// 434.390 us; speedup vs baseline: 1.5726x; 1.0056x over previous
//
#include <hip/hip_runtime.h>
#include <hip/hip_bf16.h>
#include <math.h>

// Problem constants (from reference)
#define NNODES 10000
#define MPAD   10112    // 79 * 128
#define EDGES  160000
#define EPLUS  170000   // EDGES + NNODES self-loops
#define FIN    512
#define HEADS8 8
#define CH     64
#define HC     512      // HEADS8*CH
#define NG     64       // graphs
#define NCLS   64
#define NPART  128      // bn partial blocks

typedef _Float16 f16x8 __attribute__((ext_vector_type(8)));
typedef _Float16 f16x4 __attribute__((ext_vector_type(4)));
typedef float    f32x4 __attribute__((ext_vector_type(4)));

#define GLD_LDS16(g, l)                                                        \
    __builtin_amdgcn_global_load_lds(                                          \
        (const __attribute__((address_space(1))) void*)(g),                    \
        (__attribute__((address_space(3))) void*)(l), 16, 0, 0)

// ---------------------------------------------------------------------------
// Fused prep: [0,665) dst-degree histogram + graph offsets;
//             [665,5665) fp32->fp16 convert of x_in;
//             [5665,6689) 4 weight transposes (fp32 KxN -> fp16 NxK)
// All phases independent; 256 threads/block; branch is block-uniform.
// ---------------------------------------------------------------------------
#define PREP_CNT  665
#define PREP_CONV 5000   // 10000*512/4 / 256
__global__ void prep_all(const int* __restrict__ ei, int* __restrict__ deg,
                         const int* __restrict__ batch, int* __restrict__ goff,
                         const float* __restrict__ x_in, _Float16* __restrict__ x16,
                         const float* __restrict__ Wa, const float* __restrict__ Wb,
                         const float* __restrict__ Wc, const float* __restrict__ Wd,
                         _Float16* __restrict__ Ta, _Float16* __restrict__ Tb,
                         _Float16* __restrict__ Tc, _Float16* __restrict__ Td)
{
    const int b   = blockIdx.x;
    const int tid = threadIdx.x;
    if (b < PREP_CNT) {
        int e = b * 256 + tid;
        if (e < NNODES) {
            int bb = batch[e];
            int bprev = (e == 0) ? -1 : batch[e - 1];
            for (int g = bprev + 1; g <= bb; ++g) goff[g] = e;
            if (e == NNODES - 1)
                for (int g = bb + 1; g <= NG; ++g) goff[g] = NNODES;
        }
        if (e >= EPLUS) return;
        int dst = (e < EDGES) ? ei[EDGES + e] : (e - EDGES);
        atomicAdd(&deg[dst], 1);
    } else if (b < PREP_CNT + PREP_CONV) {
        int i = (b - PREP_CNT) * 256 + tid;   // < 1,280,000 exactly
        float4 v = ((const float4*)x_in)[i];
        f16x4 o;
        o[0] = (_Float16)v.x; o[1] = (_Float16)v.y;
        o[2] = (_Float16)v.z; o[3] = (_Float16)v.w;
        ((f16x4*)x16)[i] = o;
    } else {
        int tb = b - (PREP_CNT + PREP_CONV);
        int z  = tb >> 8;            // 0..3
        int rem = tb & 255;
        int bxi = rem & 15, byi = rem >> 4;
        if (z == 3 && bxi >= 2) return;   // W3 has only 64 cols
        const float* W = (z == 0) ? Wa : (z == 1) ? Wb : (z == 2) ? Wc : Wd;
        _Float16*    T = (z == 0) ? Ta : (z == 1) ? Tb : (z == 2) ? Tc : Td;
        const int ldW = (z == 3) ? 64 : 512;
        __shared__ float t[32][33];
        int bx = bxi * 32, by = byi * 32;
        int tx = tid & 31, ty = tid >> 5;   // 32 x 8
        #pragma unroll
        for (int i = 0; i < 32; i += 8)
            t[ty + i][tx] = W[(size_t)(by + ty + i) * ldW + bx + tx];
        __syncthreads();
        #pragma unroll
        for (int i = 0; i < 32; i += 8)
            T[(size_t)(bx + ty + i) * 512 + by + tx] = (_Float16)t[tx][ty + i];
    }
}

__global__ void exscan_deg(const int* __restrict__ deg, int* __restrict__ off,
                           int* __restrict__ cursor)
{
    __shared__ int partial[256];
    const int tid = threadIdx.x;
    const int chunk = (NNODES + 255) / 256; // 40
    int begin = tid * chunk;
    int end   = begin + chunk; if (end > NNODES) end = NNODES;
    if (begin > NNODES) begin = NNODES;
    int s = 0;
    for (int i = begin; i < end; ++i) s += deg[i];
    partial[tid] = s;
    __syncthreads();
    for (int o = 1; o < 256; o <<= 1) {
        int v = (tid >= o) ? partial[tid - o] : 0;
        __syncthreads();
        partial[tid] += v;
        __syncthreads();
    }
    int run = (tid > 0) ? partial[tid - 1] : 0;  // exclusive prefix
    for (int i = begin; i < end; ++i) {
        off[i] = run; cursor[i] = run; run += deg[i];
    }
    if (tid == 255) off[NNODES] = run; // == EPLUS
}

__global__ void scatter_edges(const int* __restrict__ ei, int* __restrict__ cursor,
                              int* __restrict__ csr)
{
    int e = blockIdx.x * blockDim.x + threadIdx.x;
    if (e >= EPLUS) return;
    int srcN, dstN;
    if (e < EDGES) { srcN = ei[e]; dstN = ei[EDGES + e]; }
    else           { srcN = dstN = e - EDGES; }
    int pos = atomicAdd(&cursor[dstN], 1);
    csr[pos] = srcN;
}

// ---------------------------------------------------------------------------
// fp16 MFMA GEMM: C[M,N] = A16[M,K] @ Bt16[N,K]^T (+bias), 128x64 tile.
// Optional FUSED per-head attention scores: a 64-col tile == one head, so
// ssrc[row,head] = sum_c C[row, head*64+c]*a_s[head*64+c] is completed
// in-block from fp32 accumulators (butterfly over 16 lanes + LDS wx-combine).
// ---------------------------------------------------------------------------
__global__ __launch_bounds__(256) void gemm_f16_mfma(
    const _Float16* __restrict__ A16, const _Float16* __restrict__ Bt16,
    const float* __restrict__ bias, float* __restrict__ Cp,
    _Float16* __restrict__ C16,
    float* __restrict__ ssrc, float* __restrict__ sdst,
    const float* __restrict__ a_s, const float* __restrict__ a_d,
    int M, int Nn, int K)
{
    __shared__ _Float16 As[128 * 32] __attribute__((aligned(16)));
    __shared__ _Float16 Bs[64 * 32]  __attribute__((aligned(16)));
    __shared__ float sS[2][128];
    __shared__ float sD[2][128];
    const int tid  = threadIdx.x;
    const int wave = tid >> 6;
    const int lane = tid & 63;
    const int row0 = blockIdx.y * 128;
    const int col0 = blockIdx.x * 64;
    const int wy = wave >> 1, wx = wave & 1;

    const int lrow = lane >> 2;
    const int lk   = (lane & 3) * 8;

    f32x4 acc[4][2] = {};

    for (int k0 = 0; k0 < K; k0 += 32) {
        if (k0) __syncthreads();
        #pragma unroll
        for (int r = 0; r < 2; ++r) {
            const int chunk = r * 4 + wave;
            const int trow  = chunk * 16 + lrow;
            GLD_LDS16(A16 + (size_t)(row0 + trow) * K + k0 + lk,
                      &As[chunk * 512]);
        }
        {
            const int trow = wave * 16 + lrow;
            GLD_LDS16(Bt16 + (size_t)(col0 + trow) * K + k0 + lk,
                      &Bs[wave * 512]);
        }
        __syncthreads();

        const int quad = lane >> 4;
        const int l16  = lane & 15;
        f16x8 af[4], bf[2];
        #pragma unroll
        for (int m = 0; m < 4; ++m)
            af[m] = *(const f16x8*)&As[(wy * 64 + m * 16 + l16) * 32 + quad * 8];
        #pragma unroll
        for (int n = 0; n < 2; ++n)
            bf[n] = *(const f16x8*)&Bs[(wx * 32 + n * 16 + l16) * 32 + quad * 8];
        #pragma unroll
        for (int m = 0; m < 4; ++m)
            #pragma unroll
            for (int n = 0; n < 2; ++n)
                acc[m][n] = __builtin_amdgcn_mfma_f32_16x16x32_f16(
                    af[m], bf[n], acc[m][n], 0, 0, 0);
    }

    const int quad = lane >> 4;
    const int l16  = lane & 15;
    #pragma unroll
    for (int m = 0; m < 4; ++m) {
        #pragma unroll
        for (int n = 0; n < 2; ++n) {
            const int col = col0 + wx * 32 + n * 16 + l16;
            const float bv = bias ? bias[col] : 0.0f;
            #pragma unroll
            for (int r = 0; r < 4; ++r) {
                const int row = row0 + wy * 64 + m * 16 + quad * 4 + r;
                if (row < M) {
                    float v = acc[m][n][r] + bv;
                    if (Cp)  Cp[(size_t)row * Nn + col] = v;
                    if (C16) C16[(size_t)row * Nn + col] = (_Float16)v;
                }
            }
        }
    }

    if (ssrc) {   // fused per-head scores (bias-less layer GEMMs)
        float a_sv[2], a_dv[2];
        #pragma unroll
        for (int n = 0; n < 2; ++n) {
            const int col = col0 + wx * 32 + n * 16 + l16;
            a_sv[n] = a_s[col & 511];
            a_dv[n] = a_d[col & 511];
        }
        #pragma unroll
        for (int m = 0; m < 4; ++m) {
            #pragma unroll
            for (int r = 0; r < 4; ++r) {
                float vs = acc[m][0][r] * a_sv[0] + acc[m][1][r] * a_sv[1];
                float vd = acc[m][0][r] * a_dv[0] + acc[m][1][r] * a_dv[1];
                vs += __shfl_xor(vs, 1); vs += __shfl_xor(vs, 2);
                vs += __shfl_xor(vs, 4); vs += __shfl_xor(vs, 8);
                vd += __shfl_xor(vd, 1); vd += __shfl_xor(vd, 2);
                vd += __shfl_xor(vd, 4); vd += __shfl_xor(vd, 8);
                if (l16 == 0) {
                    const int lr = wy * 64 + m * 16 + quad * 4 + r;
                    sS[wx][lr] = vs;
                    sD[wx][lr] = vd;
                }
            }
        }
        __syncthreads();
        if (wx == 0 && l16 == 0) {
            const int head = blockIdx.x;   // Nn==512: col tile == head
            #pragma unroll
            for (int m = 0; m < 4; ++m)
                #pragma unroll
                for (int r = 0; r < 4; ++r) {
                    const int lr = wy * 64 + m * 16 + quad * 4 + r;
                    const int row = row0 + lr;
                    if (row < M) {
                        ssrc[(size_t)row * HEADS8 + head] = sS[0][lr] + sS[1][lr];
                        sdst[(size_t)row * HEADS8 + head] = sD[0][lr] + sD[1][lr];
                    }
                }
        }
    }
}

// ---------------------------------------------------------------------------
// fp16 MFMA GEMM, N=64 (layer 3) with fused NH=1 scores.
// ---------------------------------------------------------------------------
__global__ __launch_bounds__(256) void gemm_f16_mfma_n64(
    const _Float16* __restrict__ A16, const _Float16* __restrict__ Bt16,
    _Float16* __restrict__ C16,
    float* __restrict__ ssrc, float* __restrict__ sdst,
    const float* __restrict__ a_s, const float* __restrict__ a_d, int M)
{
    __shared__ _Float16 As[64 * 32] __attribute__((aligned(16)));
    __shared__ _Float16 Bs[64 * 32] __attribute__((aligned(16)));
    __shared__ float sS[2][64];
    __shared__ float sD[2][64];
    const int tid  = threadIdx.x;
    const int wave = tid >> 6;
    const int lane = tid & 63;
    const int row0 = blockIdx.x * 64;
    const int wy = wave >> 1, wx = wave & 1;

    const int lrow = lane >> 2;
    const int lk   = (lane & 3) * 8;

    f32x4 acc[2][2] = {};

    for (int k0 = 0; k0 < 512; k0 += 32) {
        if (k0) __syncthreads();
        {
            const int trow = wave * 16 + lrow;
            GLD_LDS16(A16 + (size_t)(row0 + trow) * 512 + k0 + lk, &As[wave * 512]);
            GLD_LDS16(Bt16 + (size_t)trow * 512 + k0 + lk, &Bs[wave * 512]);
        }
        __syncthreads();

        const int quad = lane >> 4;
        const int l16  = lane & 15;
        f16x8 af[2], bf[2];
        #pragma unroll
        for (int m = 0; m < 2; ++m)
            af[m] = *(const f16x8*)&As[(wy * 32 + m * 16 + l16) * 32 + quad * 8];
        #pragma unroll
        for (int n = 0; n < 2; ++n)
            bf[n] = *(const f16x8*)&Bs[(wx * 32 + n * 16 + l16) * 32 + quad * 8];
        #pragma unroll
        for (int m = 0; m < 2; ++m)
            #pragma unroll
            for (int n = 0; n < 2; ++n)
                acc[m][n] = __builtin_amdgcn_mfma_f32_16x16x32_f16(
                    af[m], bf[n], acc[m][n], 0, 0, 0);
    }

    const int quad = lane >> 4;
    const int l16  = lane & 15;
    #pragma unroll
    for (int m = 0; m < 2; ++m)
        #pragma unroll
        for (int n = 0; n < 2; ++n) {
            const int col = wx * 32 + n * 16 + l16;
            #pragma unroll
            for (int r = 0; r < 4; ++r) {
                const int row = row0 + wy * 32 + m * 16 + quad * 4 + r;
                if (row < M)
                    C16[(size_t)row * 64 + col] = (_Float16)acc[m][n][r];
            }
        }

    // fused scores (heads=1)
    {
        float a_sv[2], a_dv[2];
        #pragma unroll
        for (int n = 0; n < 2; ++n) {
            const int col = wx * 32 + n * 16 + l16;
            a_sv[n] = a_s[col];
            a_dv[n] = a_d[col];
        }
        #pragma unroll
        for (int m = 0; m < 2; ++m)
            #pragma unroll
            for (int r = 0; r < 4; ++r) {
                float vs = acc[m][0][r] * a_sv[0] + acc[m][1][r] * a_sv[1];
                float vd = acc[m][0][r] * a_dv[0] + acc[m][1][r] * a_dv[1];
                vs += __shfl_xor(vs, 1); vs += __shfl_xor(vs, 2);
                vs += __shfl_xor(vs, 4); vs += __shfl_xor(vs, 8);
                vd += __shfl_xor(vd, 1); vd += __shfl_xor(vd, 2);
                vd += __shfl_xor(vd, 4); vd += __shfl_xor(vd, 8);
                if (l16 == 0) {
                    const int lr = wy * 32 + m * 16 + quad * 4 + r;
                    sS[wx][lr] = vs;
                    sD[wx][lr] = vd;
                }
            }
        __syncthreads();
        if (wx == 0 && l16 == 0) {
            #pragma unroll
            for (int m = 0; m < 2; ++m)
                #pragma unroll
                for (int r = 0; r < 4; ++r) {
                    const int lr = wy * 32 + m * 16 + quad * 4 + r;
                    const int row = row0 + lr;
                    if (row < M) {
                        ssrc[row] = sS[0][lr] + sS[1][lr];
                        sdst[row] = sD[0][lr] + sD[1][lr];
                    }
                }
        }
    }
}

// ---------------------------------------------------------------------------
// Segment-softmax aggregation, NH=8 fp16, single pass (logits O(4), exp safe;
// softmax shift-invariant). lane owns channels [8l,8l+8), head = l>>3.
// ---------------------------------------------------------------------------
__global__ __launch_bounds__(64) void gat_aggregate8(
    const _Float16* __restrict__ Hf, const float* __restrict__ ssrc,
    const float* __restrict__ sdst, const int* __restrict__ off,
    const int* __restrict__ csr, const float* __restrict__ bias,
    float* __restrict__ out)
{
    const int n    = blockIdx.x;
    const int lane = threadIdx.x;
    const int head = lane >> 3;
    const int e0 = off[n], e1 = off[n + 1];

    float4 sd0 = ((const float4*)(sdst + n * 8))[0];
    float4 sd1 = ((const float4*)(sdst + n * 8))[1];
    float sd[8] = {sd0.x, sd0.y, sd0.z, sd0.w, sd1.x, sd1.y, sd1.z, sd1.w};

    __shared__ float exL[64 * 8];
    __shared__ int   srcL[64];
    float acc[8]  = {};
    float ssum[8] = {};
    for (int base = e0; base < e1; base += 64) {
        int cnt = e1 - base; if (cnt > 64) cnt = 64;
        if (lane < cnt) {
            int s = csr[base + lane];
            srcL[lane] = s;
            float4 s0 = ((const float4*)(ssrc + s * 8))[0];
            float4 s1 = ((const float4*)(ssrc + s * 8))[1];
            float lv[8] = {s0.x, s0.y, s0.z, s0.w, s1.x, s1.y, s1.z, s1.w};
            #pragma unroll
            for (int h = 0; h < 8; ++h) {
                float l = lv[h] + sd[h];
                l = (l > 0.f) ? l : 0.2f * l;
                float ex = expf(l);
                exL[lane * 8 + h] = ex;
                ssum[h] += ex;
            }
        }
        __syncthreads();
        for (int j = 0; j < cnt; ++j) {
            const int s = srcL[j];
            f16x8 hv = *(const f16x8*)(Hf + (size_t)s * HC + lane * 8);
            const float al = exL[j * 8 + head];
            #pragma unroll
            for (int c = 0; c < 8; ++c)
                acc[c] = fmaf(al, (float)hv[c], acc[c]);
        }
        __syncthreads();
    }
    #pragma unroll
    for (int h = 0; h < 8; ++h)
        #pragma unroll
        for (int o = 1; o < 64; o <<= 1)
            ssum[h] += __shfl_xor(ssum[h], o);

    const float inv = 1.0f / (ssum[head] + 1e-16f);
    float* op = out + (size_t)n * HC + lane * 8;
    const float* bp = bias + lane * 8;
    #pragma unroll
    for (int c = 0; c < 8; ++c)
        op[c] = acc[c] * inv + bp[c];
}

// NH=1 fp16 aggregate (layer 3), single pass, lane = channel
__global__ __launch_bounds__(64) void gat_aggregate1(
    const _Float16* __restrict__ Hf, const float* __restrict__ ssrc,
    const float* __restrict__ sdst, const int* __restrict__ off,
    const int* __restrict__ csr, const float* __restrict__ bias,
    float* __restrict__ out)
{
    const int n    = blockIdx.x;
    const int lane = threadIdx.x;
    const int e0 = off[n], e1 = off[n + 1];
    const float sd = sdst[n];

    __shared__ float exL[64];
    __shared__ int   srcL[64];
    float acc = 0.f, ssum = 0.f;
    for (int base = e0; base < e1; base += 64) {
        int cnt = e1 - base; if (cnt > 64) cnt = 64;
        if (lane < cnt) {
            int s = csr[base + lane];
            srcL[lane] = s;
            float l = ssrc[s] + sd;
            l = (l > 0.f) ? l : 0.2f * l;
            float ex = expf(l);
            exL[lane] = ex;
            ssum += ex;
        }
        __syncthreads();
        for (int j = 0; j < cnt; ++j)
            acc = fmaf(exL[j], (float)Hf[(size_t)srcL[j] * 64 + lane], acc);
        __syncthreads();
    }
    #pragma unroll
    for (int o = 1; o < 64; o <<= 1)
        ssum += __shfl_xor(ssum, o);

    out[(size_t)n * 64 + lane] = acc / (ssum + 1e-16f) + bias[lane];
}

// ---------------------------------------------------------------------------
// BatchNorm: partial sums -> tiny finalize -> vectorized elementwise apply
// ---------------------------------------------------------------------------
__global__ void bn_stats_part(const float* __restrict__ x,
                              float* __restrict__ psum, float* __restrict__ psq,
                              int rows, int cols)
{
    const int c   = threadIdx.x;   // blockDim.x == cols
    const int blk = blockIdx.x;    // NPART blocks
    float s = 0.f, sq = 0.f;
    for (int r = blk; r < rows; r += NPART) {
        float v = x[(size_t)r * cols + c];
        s += v; sq += v * v;
    }
    psum[(size_t)blk * cols + c] = s;
    psq [(size_t)blk * cols + c] = sq;
}

__global__ void bn_finalize(const float* __restrict__ psum,
                            const float* __restrict__ psq,
                            const float* __restrict__ g, const float* __restrict__ be,
                            float* __restrict__ scale, float* __restrict__ shift,
                            int cols, float invN)
{
    int c = blockIdx.x * blockDim.x + threadIdx.x;
    if (c >= cols) return;
    float s = 0.f, sq = 0.f;
    for (int p = 0; p < NPART; ++p) {
        s  += psum[(size_t)p * cols + c];
        sq += psq [(size_t)p * cols + c];
    }
    float mu  = s * invN;
    float var = sq * invN - mu * mu;
    float istd = 1.0f / sqrtf(var + 1e-5f);
    float sc = g[c] * istd;
    scale[c] = sc;
    shift[c] = be[c] - mu * sc;
}

// vectorized apply: 4 consecutive elements (same 4-col group) per thread
__global__ void bn_apply(float* __restrict__ x, const float* __restrict__ res,
                         const float* __restrict__ scale, const float* __restrict__ shift,
                         _Float16* __restrict__ out16,
                         size_t total4, int colmask, int do_elu)
{
    size_t i = (size_t)blockIdx.x * blockDim.x + threadIdx.x;
    if (i >= total4) return;
    int c = (int)((i * 4) & (size_t)colmask);
    float4 xv = ((const float4*)x)[i];
    float4 sc = *(const float4*)(scale + c);
    float4 sh = *(const float4*)(shift + c);
    float v0 = xv.x * sc.x + sh.x;
    float v1 = xv.y * sc.y + sh.y;
    float v2 = xv.z * sc.z + sh.z;
    float v3 = xv.w * sc.w + sh.w;
    if (do_elu) {
        v0 = (v0 > 0.f) ? v0 : expm1f(v0);
        v1 = (v1 > 0.f) ? v1 : expm1f(v1);
        v2 = (v2 > 0.f) ? v2 : expm1f(v2);
        v3 = (v3 > 0.f) ? v3 : expm1f(v3);
    }
    if (res) {
        float4 rv = ((const float4*)res)[i];
        v0 += rv.x; v1 += rv.y; v2 += rv.z; v3 += rv.w;
    }
    ((float4*)x)[i] = make_float4(v0, v1, v2, v3);
    if (out16) {
        f16x4 o;
        o[0] = (_Float16)v0; o[1] = (_Float16)v1;
        o[2] = (_Float16)v2; o[3] = (_Float16)v3;
        ((f16x4*)out16)[i] = o;
    }
}

// ---------------------------------------------------------------------------
// Fused global-mean-pool + final linear (one block per graph)
// ---------------------------------------------------------------------------
__global__ __launch_bounds__(256) void pool_linear(
    const float* __restrict__ x, const int* __restrict__ goff,
    const float* __restrict__ W, const float* __restrict__ b,
    float* __restrict__ out)
{
    const int g    = blockIdx.x;
    const int lane = threadIdx.x & 63;   // channel
    const int wave = threadIdx.x >> 6;   // 0..3
    const int r0 = goff[g], r1 = goff[g + 1];
    float s = 0.f;
    for (int r = r0 + wave; r < r1; r += 4)
        s += x[(size_t)r * CH + lane];
    __shared__ float red[4][CH];
    __shared__ float mean_l[CH];
    red[wave][lane] = s;
    __syncthreads();
    if (wave == 0) {
        float tot = red[0][lane] + red[1][lane] + red[2][lane] + red[3][lane];
        float cnt = (float)(r1 - r0);
        mean_l[lane] = tot / fmaxf(cnt, 1.0f);
    }
    __syncthreads();
    if (threadIdx.x < NCLS) {
        const int j = threadIdx.x;
        float acc = b[j];
        for (int c = 0; c < CH; ++c)
            acc = fmaf(mean_l[c], W[c * NCLS + j], acc);
        out[g * NCLS + j] = acc;
    }
}

// ---------------------------------------------------------------------------
// Host launcher
// ---------------------------------------------------------------------------
extern "C" void kernel_launch(void* const* d_in, const int* in_sizes, int n_in,
                              void* d_out, int out_size, void* d_ws, size_t ws_size,
                              hipStream_t stream)
{
    const float* x_in  = (const float*)d_in[0];
    const int*   ei    = (const int*)  d_in[1];
    const int*   batch = (const int*)  d_in[2];
    const float* enc_W = (const float*)d_in[3];
    const float* enc_b = (const float*)d_in[4];
    const float* W1  = (const float*)d_in[5];
    const float* as1 = (const float*)d_in[6];
    const float* ad1 = (const float*)d_in[7];
    const float* b1  = (const float*)d_in[8];
    const float* g1  = (const float*)d_in[9];
    const float* be1 = (const float*)d_in[10];
    const float* W2  = (const float*)d_in[11];
    const float* as2 = (const float*)d_in[12];
    const float* ad2 = (const float*)d_in[13];
    const float* b2  = (const float*)d_in[14];
    const float* g2  = (const float*)d_in[15];
    const float* be2 = (const float*)d_in[16];
    const float* W3  = (const float*)d_in[17];
    const float* as3 = (const float*)d_in[18];
    const float* ad3 = (const float*)d_in[19];
    const float* b3  = (const float*)d_in[20];
    const float* g3  = (const float*)d_in[21];
    const float* be3 = (const float*)d_in[22];
    const float* linW = (const float*)d_in[23];
    const float* linb = (const float*)d_in[24];
    float* out = (float*)d_out;

    char* ws = (char*)d_ws;
    size_t off_b = 0;
    auto alloc = [&](size_t bytes) -> void* {
        void* p = ws + off_b;
        off_b = (off_b + bytes + 255) & ~(size_t)255;
        return p;
    };
    float*    xA     = (float*)alloc((size_t)NNODES * HC * 4);
    float*    xC     = (float*)alloc((size_t)NNODES * HC * 4);
    _Float16* f16A   = (_Float16*)alloc((size_t)MPAD * HC * 2);
    _Float16* f16B   = (_Float16*)alloc((size_t)MPAD * HC * 2);
    _Float16* H16    = (_Float16*)alloc((size_t)NNODES * HC * 2);
    _Float16* h3_16  = (_Float16*)alloc((size_t)NNODES * CH * 2);
    float*    g3o    = (float*)alloc((size_t)NNODES * CH * 4);
    _Float16* encWt  = (_Float16*)alloc((size_t)HC * FIN * 2);
    _Float16* W1t    = (_Float16*)alloc((size_t)HC * HC * 2);
    _Float16* W2t    = (_Float16*)alloc((size_t)HC * HC * 2);
    _Float16* W3t    = (_Float16*)alloc((size_t)CH * HC * 2);
    float* ssrc   = (float*)alloc((size_t)NNODES * HEADS8 * 4);
    float* sdst   = (float*)alloc((size_t)NNODES * HEADS8 * 4);
    int*   deg    = (int*)  alloc((size_t)NNODES * 4);
    int*   offp   = (int*)  alloc((size_t)(NNODES + 1) * 4);
    int*   cursor = (int*)  alloc((size_t)NNODES * 4);
    int*   csr    = (int*)  alloc((size_t)EPLUS * 4);
    int*   goff   = (int*)  alloc((size_t)(NG + 1) * 4);
    float* psum   = (float*)alloc((size_t)NPART * HC * 4);
    float* psq    = (float*)alloc((size_t)NPART * HC * 4);
    float* bnsc   = (float*)alloc(HC * 4);
    float* bnsh   = (float*)alloc(HC * 4);

    // ---- Prep: histogram+goff, x fp16 convert, weight transposes (1 kernel)
    hipMemsetAsync(deg, 0, (size_t)NNODES * 4, stream);
    prep_all<<<PREP_CNT + PREP_CONV + 1024, 256, 0, stream>>>(
        ei, deg, batch, goff, x_in, f16A, enc_W, W1, W2, W3,
        encWt, W1t, W2t, W3t);
    exscan_deg<<<1, 256, 0, stream>>>(deg, offp, cursor);
    scatter_edges<<<(EPLUS + 255) / 256, 256, 0, stream>>>(ei, cursor, csr);

    const dim3 mfma_grid(HC / 64, MPAD / 128);   // (8, 79) = 632 blocks

    // ---- Encoder: xA fp32 + f16B fp16 = x_in @ enc_W + enc_b (no scores)
    gemm_f16_mfma<<<mfma_grid, 256, 0, stream>>>(
        f16A, encWt, enc_b, xA, f16B, nullptr, nullptr, nullptr, nullptr,
        NNODES, HC, FIN);

    // ---- GAT layers 1-2 (scores fused into GEMM epilogue)
    auto run_layer = [&](const _Float16* a16, const _Float16* wt,
                         const float* res, float* gout, _Float16* out16,
                         const float* a_s, const float* a_d,
                         const float* bconv, const float* gg, const float* bb) {
        gemm_f16_mfma<<<mfma_grid, 256, 0, stream>>>(
            a16, wt, nullptr, nullptr, H16, ssrc, sdst, a_s, a_d,
            NNODES, HC, HC);
        gat_aggregate8<<<NNODES, 64, 0, stream>>>(H16, ssrc, sdst, offp, csr,
                                                  bconv, gout);
        bn_stats_part<<<NPART, HC, 0, stream>>>(gout, psum, psq, NNODES, HC);
        bn_finalize<<<2, 256, 0, stream>>>(psum, psq, gg, bb, bnsc, bnsh, HC,
                                           1.0f / NNODES);
        size_t total4 = (size_t)NNODES * HC / 4;
        bn_apply<<<(int)((total4 + 255) / 256), 256, 0, stream>>>(
            gout, res, bnsc, bnsh, out16, total4, HC - 1, 1);
    };

    // Layer 1: A=f16B, residual xA, out xC (+f16A for layer-2 GEMM)
    run_layer(f16B, W1t, xA, xC, f16A, as1, ad1, b1, g1, be1);
    // Layer 2: A=f16A, residual xC, out xA (+f16B for layer-3 GEMM)
    run_layer(f16A, W2t, xC, xA, f16B, as2, ad2, b2, g2, be2);

    // ---- Layer 3 (heads=1, C=64): fp16 MFMA GEMM with fused scores
    gemm_f16_mfma_n64<<<MPAD / 64, 256, 0, stream>>>(f16B, W3t, h3_16,
                                                     ssrc, sdst, as3, ad3,
                                                     NNODES);
    gat_aggregate1<<<NNODES, 64, 0, stream>>>(h3_16, ssrc, sdst, offp, csr,
                                              b3, g3o);
    bn_stats_part<<<NPART, CH, 0, stream>>>(g3o, psum, psq, NNODES, CH);
    bn_finalize<<<1, 64, 0, stream>>>(psum, psq, g3, be3, bnsc, bnsh, CH,
                                      1.0f / NNODES);
    {
        size_t total4 = (size_t)NNODES * CH / 4;
        bn_apply<<<(int)((total4 + 255) / 256), 256, 0, stream>>>(
            g3o, nullptr, bnsc, bnsh, nullptr, total4, CH - 1, 0);
    }

    // ---- Fused global mean pool + final linear
    pool_linear<<<NG, 256, 0, stream>>>(g3o, goff, linW, linb, out);
}

// Round 9
// 422.493 us; speedup vs baseline: 1.6169x; 1.0282x over previous
//
#include <hip/hip_runtime.h>
#include <hip/hip_bf16.h>
#include <math.h>

// Problem constants (from reference)
#define NNODES 10000
#define MPAD   10112    // 79 * 128
#define EDGES  160000
#define EPLUS  170000   // EDGES + NNODES self-loops
#define FIN    512
#define HEADS8 8
#define CH     64
#define HC     512      // HEADS8*CH
#define NG     64       // graphs
#define NCLS   64
#define NPART  128      // bn partial blocks

typedef _Float16 f16x8 __attribute__((ext_vector_type(8)));
typedef _Float16 f16x4 __attribute__((ext_vector_type(4)));
typedef _Float16 f16x2 __attribute__((ext_vector_type(2)));
typedef float    f32x4 __attribute__((ext_vector_type(4)));

#define GLD_LDS16(g, l)                                                        \
    __builtin_amdgcn_global_load_lds(                                          \
        (const __attribute__((address_space(1))) void*)(g),                    \
        (__attribute__((address_space(3))) void*)(l), 16, 0, 0)

// ---------------------------------------------------------------------------
// Fused prep: [0,665) dst-degree histogram + graph offsets;
//             [665,5665) fp32->fp16 convert of x_in;
//             [5665,...) 4 weight transposes (fp32 KxN -> fp16 NxK)
// ---------------------------------------------------------------------------
#define PREP_CNT  665
#define PREP_CONV 5000   // 10000*512/4 / 256
__global__ void prep_all(const int* __restrict__ ei, int* __restrict__ deg,
                         const int* __restrict__ batch, int* __restrict__ goff,
                         const float* __restrict__ x_in, _Float16* __restrict__ x16,
                         const float* __restrict__ Wa, const float* __restrict__ Wb,
                         const float* __restrict__ Wc, const float* __restrict__ Wd,
                         _Float16* __restrict__ Ta, _Float16* __restrict__ Tb,
                         _Float16* __restrict__ Tc, _Float16* __restrict__ Td)
{
    const int b   = blockIdx.x;
    const int tid = threadIdx.x;
    if (b < PREP_CNT) {
        int e = b * 256 + tid;
        if (e < NNODES) {
            int bb = batch[e];
            int bprev = (e == 0) ? -1 : batch[e - 1];
            for (int g = bprev + 1; g <= bb; ++g) goff[g] = e;
            if (e == NNODES - 1)
                for (int g = bb + 1; g <= NG; ++g) goff[g] = NNODES;
        }
        if (e >= EPLUS) return;
        int dst = (e < EDGES) ? ei[EDGES + e] : (e - EDGES);
        atomicAdd(&deg[dst], 1);
    } else if (b < PREP_CNT + PREP_CONV) {
        int i = (b - PREP_CNT) * 256 + tid;
        float4 v = ((const float4*)x_in)[i];
        f16x4 o;
        o[0] = (_Float16)v.x; o[1] = (_Float16)v.y;
        o[2] = (_Float16)v.z; o[3] = (_Float16)v.w;
        ((f16x4*)x16)[i] = o;
    } else {
        int tb = b - (PREP_CNT + PREP_CONV);
        int z  = tb >> 8;            // 0..3
        int rem = tb & 255;
        int bxi = rem & 15, byi = rem >> 4;
        if (z == 3 && bxi >= 2) return;   // W3 has only 64 cols
        const float* W = (z == 0) ? Wa : (z == 1) ? Wb : (z == 2) ? Wc : Wd;
        _Float16*    T = (z == 0) ? Ta : (z == 1) ? Tb : (z == 2) ? Tc : Td;
        const int ldW = (z == 3) ? 64 : 512;
        __shared__ float t[32][33];
        int bx = bxi * 32, by = byi * 32;
        int tx = tid & 31, ty = tid >> 5;   // 32 x 8
        #pragma unroll
        for (int i = 0; i < 32; i += 8)
            t[ty + i][tx] = W[(size_t)(by + ty + i) * ldW + bx + tx];
        __syncthreads();
        #pragma unroll
        for (int i = 0; i < 32; i += 8)
            T[(size_t)(bx + ty + i) * 512 + by + tx] = (_Float16)t[tx][ty + i];
    }
}

__global__ void exscan_deg(const int* __restrict__ deg, int* __restrict__ off,
                           int* __restrict__ cursor)
{
    __shared__ int partial[256];
    const int tid = threadIdx.x;
    const int chunk = (NNODES + 255) / 256; // 40
    int begin = tid * chunk;
    int end   = begin + chunk; if (end > NNODES) end = NNODES;
    if (begin > NNODES) begin = NNODES;
    int s = 0;
    for (int i = begin; i < end; ++i) s += deg[i];
    partial[tid] = s;
    __syncthreads();
    for (int o = 1; o < 256; o <<= 1) {
        int v = (tid >= o) ? partial[tid - o] : 0;
        __syncthreads();
        partial[tid] += v;
        __syncthreads();
    }
    int run = (tid > 0) ? partial[tid - 1] : 0;  // exclusive prefix
    for (int i = begin; i < end; ++i) {
        off[i] = run; cursor[i] = run; run += deg[i];
    }
    if (tid == 255) off[NNODES] = run; // == EPLUS
}

__global__ void scatter_edges(const int* __restrict__ ei, int* __restrict__ cursor,
                              int* __restrict__ csr)
{
    int e = blockIdx.x * blockDim.x + threadIdx.x;
    if (e >= EPLUS) return;
    int srcN, dstN;
    if (e < EDGES) { srcN = ei[e]; dstN = ei[EDGES + e]; }
    else           { srcN = dstN = e - EDGES; }
    int pos = atomicAdd(&cursor[dstN], 1);
    csr[pos] = srcN;
}

// ---------------------------------------------------------------------------
// fp16 MFMA GEMM: C[M,N] = A16[M,K] @ Bt16[N,K]^T (+bias), 128x64 tile.
// Optional fused per-head attention scores (64-col tile == one head).
// ---------------------------------------------------------------------------
__global__ __launch_bounds__(256) void gemm_f16_mfma(
    const _Float16* __restrict__ A16, const _Float16* __restrict__ Bt16,
    const float* __restrict__ bias, _Float16* __restrict__ C16,
    float* __restrict__ ssrc, float* __restrict__ sdst,
    const float* __restrict__ a_s, const float* __restrict__ a_d,
    int M, int Nn, int K)
{
    __shared__ _Float16 As[128 * 32] __attribute__((aligned(16)));
    __shared__ _Float16 Bs[64 * 32]  __attribute__((aligned(16)));
    __shared__ float sS[2][128];
    __shared__ float sD[2][128];
    const int tid  = threadIdx.x;
    const int wave = tid >> 6;
    const int lane = tid & 63;
    const int row0 = blockIdx.y * 128;
    const int col0 = blockIdx.x * 64;
    const int wy = wave >> 1, wx = wave & 1;

    const int lrow = lane >> 2;
    const int lk   = (lane & 3) * 8;

    f32x4 acc[4][2] = {};

    for (int k0 = 0; k0 < K; k0 += 32) {
        if (k0) __syncthreads();
        #pragma unroll
        for (int r = 0; r < 2; ++r) {
            const int chunk = r * 4 + wave;
            const int trow  = chunk * 16 + lrow;
            GLD_LDS16(A16 + (size_t)(row0 + trow) * K + k0 + lk,
                      &As[chunk * 512]);
        }
        {
            const int trow = wave * 16 + lrow;
            GLD_LDS16(Bt16 + (size_t)(col0 + trow) * K + k0 + lk,
                      &Bs[wave * 512]);
        }
        __syncthreads();

        const int quad = lane >> 4;
        const int l16  = lane & 15;
        f16x8 af[4], bf[2];
        #pragma unroll
        for (int m = 0; m < 4; ++m)
            af[m] = *(const f16x8*)&As[(wy * 64 + m * 16 + l16) * 32 + quad * 8];
        #pragma unroll
        for (int n = 0; n < 2; ++n)
            bf[n] = *(const f16x8*)&Bs[(wx * 32 + n * 16 + l16) * 32 + quad * 8];
        #pragma unroll
        for (int m = 0; m < 4; ++m)
            #pragma unroll
            for (int n = 0; n < 2; ++n)
                acc[m][n] = __builtin_amdgcn_mfma_f32_16x16x32_f16(
                    af[m], bf[n], acc[m][n], 0, 0, 0);
    }

    const int quad = lane >> 4;
    const int l16  = lane & 15;
    #pragma unroll
    for (int m = 0; m < 4; ++m) {
        #pragma unroll
        for (int n = 0; n < 2; ++n) {
            const int col = col0 + wx * 32 + n * 16 + l16;
            const float bv = bias ? bias[col] : 0.0f;
            #pragma unroll
            for (int r = 0; r < 4; ++r) {
                const int row = row0 + wy * 64 + m * 16 + quad * 4 + r;
                if (row < M)
                    C16[(size_t)row * Nn + col] = (_Float16)(acc[m][n][r] + bv);
            }
        }
    }

    if (ssrc) {   // fused per-head scores (bias-less layer GEMMs)
        float a_sv[2], a_dv[2];
        #pragma unroll
        for (int n = 0; n < 2; ++n) {
            const int col = col0 + wx * 32 + n * 16 + l16;
            a_sv[n] = a_s[col & 511];
            a_dv[n] = a_d[col & 511];
        }
        #pragma unroll
        for (int m = 0; m < 4; ++m) {
            #pragma unroll
            for (int r = 0; r < 4; ++r) {
                float vs = acc[m][0][r] * a_sv[0] + acc[m][1][r] * a_sv[1];
                float vd = acc[m][0][r] * a_dv[0] + acc[m][1][r] * a_dv[1];
                vs += __shfl_xor(vs, 1); vs += __shfl_xor(vs, 2);
                vs += __shfl_xor(vs, 4); vs += __shfl_xor(vs, 8);
                vd += __shfl_xor(vd, 1); vd += __shfl_xor(vd, 2);
                vd += __shfl_xor(vd, 4); vd += __shfl_xor(vd, 8);
                if (l16 == 0) {
                    const int lr = wy * 64 + m * 16 + quad * 4 + r;
                    sS[wx][lr] = vs;
                    sD[wx][lr] = vd;
                }
            }
        }
        __syncthreads();
        if (wx == 0 && l16 == 0) {
            const int head = blockIdx.x;   // Nn==512: col tile == head
            #pragma unroll
            for (int m = 0; m < 4; ++m)
                #pragma unroll
                for (int r = 0; r < 4; ++r) {
                    const int lr = wy * 64 + m * 16 + quad * 4 + r;
                    const int row = row0 + lr;
                    if (row < M) {
                        ssrc[(size_t)row * HEADS8 + head] = sS[0][lr] + sS[1][lr];
                        sdst[(size_t)row * HEADS8 + head] = sD[0][lr] + sD[1][lr];
                    }
                }
        }
    }
}

// ---------------------------------------------------------------------------
// fp16 MFMA GEMM, N=64 (layer 3) with fused NH=1 scores.
// ---------------------------------------------------------------------------
__global__ __launch_bounds__(256) void gemm_f16_mfma_n64(
    const _Float16* __restrict__ A16, const _Float16* __restrict__ Bt16,
    _Float16* __restrict__ C16,
    float* __restrict__ ssrc, float* __restrict__ sdst,
    const float* __restrict__ a_s, const float* __restrict__ a_d, int M)
{
    __shared__ _Float16 As[64 * 32] __attribute__((aligned(16)));
    __shared__ _Float16 Bs[64 * 32] __attribute__((aligned(16)));
    __shared__ float sS[2][64];
    __shared__ float sD[2][64];
    const int tid  = threadIdx.x;
    const int wave = tid >> 6;
    const int lane = tid & 63;
    const int row0 = blockIdx.x * 64;
    const int wy = wave >> 1, wx = wave & 1;

    const int lrow = lane >> 2;
    const int lk   = (lane & 3) * 8;

    f32x4 acc[2][2] = {};

    for (int k0 = 0; k0 < 512; k0 += 32) {
        if (k0) __syncthreads();
        {
            const int trow = wave * 16 + lrow;
            GLD_LDS16(A16 + (size_t)(row0 + trow) * 512 + k0 + lk, &As[wave * 512]);
            GLD_LDS16(Bt16 + (size_t)trow * 512 + k0 + lk, &Bs[wave * 512]);
        }
        __syncthreads();

        const int quad = lane >> 4;
        const int l16  = lane & 15;
        f16x8 af[2], bf[2];
        #pragma unroll
        for (int m = 0; m < 2; ++m)
            af[m] = *(const f16x8*)&As[(wy * 32 + m * 16 + l16) * 32 + quad * 8];
        #pragma unroll
        for (int n = 0; n < 2; ++n)
            bf[n] = *(const f16x8*)&Bs[(wx * 32 + n * 16 + l16) * 32 + quad * 8];
        #pragma unroll
        for (int m = 0; m < 2; ++m)
            #pragma unroll
            for (int n = 0; n < 2; ++n)
                acc[m][n] = __builtin_amdgcn_mfma_f32_16x16x32_f16(
                    af[m], bf[n], acc[m][n], 0, 0, 0);
    }

    const int quad = lane >> 4;
    const int l16  = lane & 15;
    #pragma unroll
    for (int m = 0; m < 2; ++m)
        #pragma unroll
        for (int n = 0; n < 2; ++n) {
            const int col = wx * 32 + n * 16 + l16;
            #pragma unroll
            for (int r = 0; r < 4; ++r) {
                const int row = row0 + wy * 32 + m * 16 + quad * 4 + r;
                if (row < M)
                    C16[(size_t)row * 64 + col] = (_Float16)acc[m][n][r];
            }
        }

    // fused scores (heads=1)
    {
        float a_sv[2], a_dv[2];
        #pragma unroll
        for (int n = 0; n < 2; ++n) {
            const int col = wx * 32 + n * 16 + l16;
            a_sv[n] = a_s[col];
            a_dv[n] = a_d[col];
        }
        #pragma unroll
        for (int m = 0; m < 2; ++m)
            #pragma unroll
            for (int r = 0; r < 4; ++r) {
                float vs = acc[m][0][r] * a_sv[0] + acc[m][1][r] * a_sv[1];
                float vd = acc[m][0][r] * a_dv[0] + acc[m][1][r] * a_dv[1];
                vs += __shfl_xor(vs, 1); vs += __shfl_xor(vs, 2);
                vs += __shfl_xor(vs, 4); vs += __shfl_xor(vs, 8);
                vd += __shfl_xor(vd, 1); vd += __shfl_xor(vd, 2);
                vd += __shfl_xor(vd, 4); vd += __shfl_xor(vd, 8);
                if (l16 == 0) {
                    const int lr = wy * 32 + m * 16 + quad * 4 + r;
                    sS[wx][lr] = vs;
                    sD[wx][lr] = vd;
                }
            }
        __syncthreads();
        if (wx == 0 && l16 == 0) {
            #pragma unroll
            for (int m = 0; m < 2; ++m)
                #pragma unroll
                for (int r = 0; r < 4; ++r) {
                    const int lr = wy * 32 + m * 16 + quad * 4 + r;
                    const int row = row0 + lr;
                    if (row < M) {
                        ssrc[row] = sS[0][lr] + sS[1][lr];
                        sdst[row] = sD[0][lr] + sD[1][lr];
                    }
                }
        }
    }
}

// ---------------------------------------------------------------------------
// Segment-softmax aggregation, NH=8 fp16, single pass; f16 output.
// ---------------------------------------------------------------------------
__global__ __launch_bounds__(64) void gat_aggregate8(
    const _Float16* __restrict__ Hf, const float* __restrict__ ssrc,
    const float* __restrict__ sdst, const int* __restrict__ off,
    const int* __restrict__ csr, const float* __restrict__ bias,
    _Float16* __restrict__ out)
{
    const int n    = blockIdx.x;
    const int lane = threadIdx.x;
    const int head = lane >> 3;
    const int e0 = off[n], e1 = off[n + 1];

    float4 sd0 = ((const float4*)(sdst + n * 8))[0];
    float4 sd1 = ((const float4*)(sdst + n * 8))[1];
    float sd[8] = {sd0.x, sd0.y, sd0.z, sd0.w, sd1.x, sd1.y, sd1.z, sd1.w};

    __shared__ float exL[64 * 8];
    __shared__ int   srcL[64];
    float acc[8]  = {};
    float ssum[8] = {};
    for (int base = e0; base < e1; base += 64) {
        int cnt = e1 - base; if (cnt > 64) cnt = 64;
        if (lane < cnt) {
            int s = csr[base + lane];
            srcL[lane] = s;
            float4 s0 = ((const float4*)(ssrc + s * 8))[0];
            float4 s1 = ((const float4*)(ssrc + s * 8))[1];
            float lv[8] = {s0.x, s0.y, s0.z, s0.w, s1.x, s1.y, s1.z, s1.w};
            #pragma unroll
            for (int h = 0; h < 8; ++h) {
                float l = lv[h] + sd[h];
                l = (l > 0.f) ? l : 0.2f * l;
                float ex = __expf(l);
                exL[lane * 8 + h] = ex;
                ssum[h] += ex;
            }
        }
        __syncthreads();
        for (int j = 0; j < cnt; ++j) {
            const int s = srcL[j];
            f16x8 hv = *(const f16x8*)(Hf + (size_t)s * HC + lane * 8);
            const float al = exL[j * 8 + head];
            #pragma unroll
            for (int c = 0; c < 8; ++c)
                acc[c] = fmaf(al, (float)hv[c], acc[c]);
        }
        __syncthreads();
    }
    #pragma unroll
    for (int h = 0; h < 8; ++h)
        #pragma unroll
        for (int o = 1; o < 64; o <<= 1)
            ssum[h] += __shfl_xor(ssum[h], o);

    const float inv = 1.0f / (ssum[head] + 1e-16f);
    const float* bp = bias + lane * 8;
    f16x8 ov;
    #pragma unroll
    for (int c = 0; c < 8; ++c)
        ov[c] = (_Float16)(acc[c] * inv + bp[c]);
    *(f16x8*)(out + (size_t)n * HC + lane * 8) = ov;
}

// NH=1 fp16 aggregate (layer 3), single pass, lane = channel, fp32 out
__global__ __launch_bounds__(64) void gat_aggregate1(
    const _Float16* __restrict__ Hf, const float* __restrict__ ssrc,
    const float* __restrict__ sdst, const int* __restrict__ off,
    const int* __restrict__ csr, const float* __restrict__ bias,
    float* __restrict__ out)
{
    const int n    = blockIdx.x;
    const int lane = threadIdx.x;
    const int e0 = off[n], e1 = off[n + 1];
    const float sd = sdst[n];

    __shared__ float exL[64];
    __shared__ int   srcL[64];
    float acc = 0.f, ssum = 0.f;
    for (int base = e0; base < e1; base += 64) {
        int cnt = e1 - base; if (cnt > 64) cnt = 64;
        if (lane < cnt) {
            int s = csr[base + lane];
            srcL[lane] = s;
            float l = ssrc[s] + sd;
            l = (l > 0.f) ? l : 0.2f * l;
            float ex = __expf(l);
            exL[lane] = ex;
            ssum += ex;
        }
        __syncthreads();
        for (int j = 0; j < cnt; ++j)
            acc = fmaf(exL[j], (float)Hf[(size_t)srcL[j] * 64 + lane], acc);
        __syncthreads();
    }
    #pragma unroll
    for (int o = 1; o < 64; o <<= 1)
        ssum += __shfl_xor(ssum, o);

    out[(size_t)n * 64 + lane] = acc / (ssum + 1e-16f) + bias[lane];
}

// ---------------------------------------------------------------------------
// BatchNorm (f16 activations): partial sums -> finalize -> vectorized apply
// ---------------------------------------------------------------------------
// 256 threads, 2 adjacent cols each (cols must be 512)
__global__ void bn_stats_f16(const _Float16* __restrict__ x,
                             float* __restrict__ psum, float* __restrict__ psq,
                             int rows)
{
    const int c2  = threadIdx.x;   // owns cols 2*c2, 2*c2+1
    const int blk = blockIdx.x;
    float s0 = 0.f, q0 = 0.f, s1 = 0.f, q1 = 0.f;
    for (int r = blk; r < rows; r += NPART) {
        f16x2 v = *(const f16x2*)(x + (size_t)r * HC + c2 * 2);
        float a = (float)v[0], b = (float)v[1];
        s0 += a; q0 += a * a;
        s1 += b; q1 += b * b;
    }
    psum[(size_t)blk * HC + c2 * 2]     = s0;
    psum[(size_t)blk * HC + c2 * 2 + 1] = s1;
    psq [(size_t)blk * HC + c2 * 2]     = q0;
    psq [(size_t)blk * HC + c2 * 2 + 1] = q1;
}

// fp32 stats (layer 3, cols=64, blockDim=64)
__global__ void bn_stats_part(const float* __restrict__ x,
                              float* __restrict__ psum, float* __restrict__ psq,
                              int rows, int cols)
{
    const int c   = threadIdx.x;
    const int blk = blockIdx.x;
    float s = 0.f, sq = 0.f;
    for (int r = blk; r < rows; r += NPART) {
        float v = x[(size_t)r * cols + c];
        s += v; sq += v * v;
    }
    psum[(size_t)blk * cols + c] = s;
    psq [(size_t)blk * cols + c] = sq;
}

__global__ void bn_finalize(const float* __restrict__ psum,
                            const float* __restrict__ psq,
                            const float* __restrict__ g, const float* __restrict__ be,
                            float* __restrict__ scale, float* __restrict__ shift,
                            int cols, float invN)
{
    int c = blockIdx.x * blockDim.x + threadIdx.x;
    if (c >= cols) return;
    float s = 0.f, sq = 0.f;
    for (int p = 0; p < NPART; ++p) {
        s  += psum[(size_t)p * cols + c];
        sq += psq [(size_t)p * cols + c];
    }
    float mu  = s * invN;
    float var = sq * invN - mu * mu;
    float istd = 1.0f / sqrtf(var + 1e-5f);
    float sc = g[c] * istd;
    scale[c] = sc;
    shift[c] = be[c] - mu * sc;
}

// f16 in, f16 residual, f16 out: v = elu(x*scale + shift) + res
__global__ void bn_apply16(const _Float16* __restrict__ xin,
                           const _Float16* __restrict__ res,
                           const float* __restrict__ scale,
                           const float* __restrict__ shift,
                           _Float16* __restrict__ out, size_t total4, int colmask)
{
    size_t i = (size_t)blockIdx.x * blockDim.x + threadIdx.x;
    if (i >= total4) return;
    int c = (int)((i * 4) & (size_t)colmask);
    f16x4 xv = ((const f16x4*)xin)[i];
    float4 sc = *(const float4*)(scale + c);
    float4 sh = *(const float4*)(shift + c);
    f16x4 rv = ((const f16x4*)res)[i];
    float v0 = (float)xv[0] * sc.x + sh.x;
    float v1 = (float)xv[1] * sc.y + sh.y;
    float v2 = (float)xv[2] * sc.z + sh.z;
    float v3 = (float)xv[3] * sc.w + sh.w;
    v0 = (v0 > 0.f) ? v0 : expm1f(v0);
    v1 = (v1 > 0.f) ? v1 : expm1f(v1);
    v2 = (v2 > 0.f) ? v2 : expm1f(v2);
    v3 = (v3 > 0.f) ? v3 : expm1f(v3);
    f16x4 o;
    o[0] = (_Float16)(v0 + (float)rv[0]);
    o[1] = (_Float16)(v1 + (float)rv[1]);
    o[2] = (_Float16)(v2 + (float)rv[2]);
    o[3] = (_Float16)(v3 + (float)rv[3]);
    ((f16x4*)out)[i] = o;
}

// fp32 in-place apply (layer 3: no elu, no residual)
__global__ void bn_apply(float* __restrict__ x,
                         const float* __restrict__ scale, const float* __restrict__ shift,
                         size_t total4, int colmask)
{
    size_t i = (size_t)blockIdx.x * blockDim.x + threadIdx.x;
    if (i >= total4) return;
    int c = (int)((i * 4) & (size_t)colmask);
    float4 xv = ((const float4*)x)[i];
    float4 sc = *(const float4*)(scale + c);
    float4 sh = *(const float4*)(shift + c);
    ((float4*)x)[i] = make_float4(xv.x * sc.x + sh.x, xv.y * sc.y + sh.y,
                                  xv.z * sc.z + sh.z, xv.w * sc.w + sh.w);
}

// ---------------------------------------------------------------------------
// Fused global-mean-pool + final linear (one block per graph)
// ---------------------------------------------------------------------------
__global__ __launch_bounds__(256) void pool_linear(
    const float* __restrict__ x, const int* __restrict__ goff,
    const float* __restrict__ W, const float* __restrict__ b,
    float* __restrict__ out)
{
    const int g    = blockIdx.x;
    const int lane = threadIdx.x & 63;   // channel
    const int wave = threadIdx.x >> 6;   // 0..3
    const int r0 = goff[g], r1 = goff[g + 1];
    float s = 0.f;
    for (int r = r0 + wave; r < r1; r += 4)
        s += x[(size_t)r * CH + lane];
    __shared__ float red[4][CH];
    __shared__ float mean_l[CH];
    red[wave][lane] = s;
    __syncthreads();
    if (wave == 0) {
        float tot = red[0][lane] + red[1][lane] + red[2][lane] + red[3][lane];
        float cnt = (float)(r1 - r0);
        mean_l[lane] = tot / fmaxf(cnt, 1.0f);
    }
    __syncthreads();
    if (threadIdx.x < NCLS) {
        const int j = threadIdx.x;
        float acc = b[j];
        for (int c = 0; c < CH; ++c)
            acc = fmaf(mean_l[c], W[c * NCLS + j], acc);
        out[g * NCLS + j] = acc;
    }
}

// ---------------------------------------------------------------------------
// Host launcher
// ---------------------------------------------------------------------------
extern "C" void kernel_launch(void* const* d_in, const int* in_sizes, int n_in,
                              void* d_out, int out_size, void* d_ws, size_t ws_size,
                              hipStream_t stream)
{
    const float* x_in  = (const float*)d_in[0];
    const int*   ei    = (const int*)  d_in[1];
    const int*   batch = (const int*)  d_in[2];
    const float* enc_W = (const float*)d_in[3];
    const float* enc_b = (const float*)d_in[4];
    const float* W1  = (const float*)d_in[5];
    const float* as1 = (const float*)d_in[6];
    const float* ad1 = (const float*)d_in[7];
    const float* b1  = (const float*)d_in[8];
    const float* g1  = (const float*)d_in[9];
    const float* be1 = (const float*)d_in[10];
    const float* W2  = (const float*)d_in[11];
    const float* as2 = (const float*)d_in[12];
    const float* ad2 = (const float*)d_in[13];
    const float* b2  = (const float*)d_in[14];
    const float* g2  = (const float*)d_in[15];
    const float* be2 = (const float*)d_in[16];
    const float* W3  = (const float*)d_in[17];
    const float* as3 = (const float*)d_in[18];
    const float* ad3 = (const float*)d_in[19];
    const float* b3  = (const float*)d_in[20];
    const float* g3  = (const float*)d_in[21];
    const float* be3 = (const float*)d_in[22];
    const float* linW = (const float*)d_in[23];
    const float* linb = (const float*)d_in[24];
    float* out = (float*)d_out;

    char* ws = (char*)d_ws;
    size_t off_b = 0;
    auto alloc = [&](size_t bytes) -> void* {
        void* p = ws + off_b;
        off_b = (off_b + bytes + 255) & ~(size_t)255;
        return p;
    };
    _Float16* f16A   = (_Float16*)alloc((size_t)MPAD * HC * 2);   // act buf A
    _Float16* f16B   = (_Float16*)alloc((size_t)MPAD * HC * 2);   // act buf B
    _Float16* H16    = (_Float16*)alloc((size_t)NNODES * HC * 2); // GAT features
    _Float16* g16    = (_Float16*)alloc((size_t)NNODES * HC * 2); // aggregate out
    _Float16* h3_16  = (_Float16*)alloc((size_t)NNODES * CH * 2);
    float*    g3o    = (float*)alloc((size_t)NNODES * CH * 4);
    _Float16* encWt  = (_Float16*)alloc((size_t)HC * FIN * 2);
    _Float16* W1t    = (_Float16*)alloc((size_t)HC * HC * 2);
    _Float16* W2t    = (_Float16*)alloc((size_t)HC * HC * 2);
    _Float16* W3t    = (_Float16*)alloc((size_t)CH * HC * 2);
    float* ssrc   = (float*)alloc((size_t)NNODES * HEADS8 * 4);
    float* sdst   = (float*)alloc((size_t)NNODES * HEADS8 * 4);
    int*   deg    = (int*)  alloc((size_t)NNODES * 4);
    int*   offp   = (int*)  alloc((size_t)(NNODES + 1) * 4);
    int*   cursor = (int*)  alloc((size_t)NNODES * 4);
    int*   csr    = (int*)  alloc((size_t)EPLUS * 4);
    int*   goff   = (int*)  alloc((size_t)(NG + 1) * 4);
    float* psum   = (float*)alloc((size_t)NPART * HC * 4);
    float* psq    = (float*)alloc((size_t)NPART * HC * 4);
    float* bnsc   = (float*)alloc(HC * 4);
    float* bnsh   = (float*)alloc(HC * 4);

    // ---- Prep: histogram+goff, x fp16 convert, weight transposes (1 kernel)
    hipMemsetAsync(deg, 0, (size_t)NNODES * 4, stream);
    prep_all<<<PREP_CNT + PREP_CONV + 1024, 256, 0, stream>>>(
        ei, deg, batch, goff, x_in, f16A, enc_W, W1, W2, W3,
        encWt, W1t, W2t, W3t);
    exscan_deg<<<1, 256, 0, stream>>>(deg, offp, cursor);
    scatter_edges<<<(EPLUS + 255) / 256, 256, 0, stream>>>(ei, cursor, csr);

    const dim3 mfma_grid(HC / 64, MPAD / 128);   // (8, 79) = 632 blocks

    // ---- Encoder: f16B = f16(x_in @ enc_W + enc_b)  (fp16-only activations)
    gemm_f16_mfma<<<mfma_grid, 256, 0, stream>>>(
        f16A, encWt, enc_b, f16B, nullptr, nullptr, nullptr, nullptr,
        NNODES, HC, FIN);

    // ---- GAT layers 1-2 (scores fused into GEMM; fp16 activation pipeline)
    auto run_layer = [&](const _Float16* a16, const _Float16* wt,
                         const _Float16* res16, _Float16* out16,
                         const float* a_s, const float* a_d,
                         const float* bconv, const float* gg, const float* bb) {
        gemm_f16_mfma<<<mfma_grid, 256, 0, stream>>>(
            a16, wt, nullptr, H16, ssrc, sdst, a_s, a_d, NNODES, HC, HC);
        gat_aggregate8<<<NNODES, 64, 0, stream>>>(H16, ssrc, sdst, offp, csr,
                                                  bconv, g16);
        bn_stats_f16<<<NPART, 256, 0, stream>>>(g16, psum, psq, NNODES);
        bn_finalize<<<2, 256, 0, stream>>>(psum, psq, gg, bb, bnsc, bnsh, HC,
                                           1.0f / NNODES);
        size_t total4 = (size_t)NNODES * HC / 4;
        bn_apply16<<<(int)((total4 + 255) / 256), 256, 0, stream>>>(
            g16, res16, bnsc, bnsh, out16, total4, HC - 1);
    };

    // Layer 1: A=f16B, residual f16B, out f16A (A+res for layer 2)
    run_layer(f16B, W1t, f16B, f16A, as1, ad1, b1, g1, be1);
    // Layer 2: A=f16A, residual f16A, out f16B (A for layer 3)
    run_layer(f16A, W2t, f16A, f16B, as2, ad2, b2, g2, be2);

    // ---- Layer 3 (heads=1, C=64): fp16 MFMA GEMM with fused scores
    gemm_f16_mfma_n64<<<MPAD / 64, 256, 0, stream>>>(f16B, W3t, h3_16,
                                                     ssrc, sdst, as3, ad3,
                                                     NNODES);
    gat_aggregate1<<<NNODES, 64, 0, stream>>>(h3_16, ssrc, sdst, offp, csr,
                                              b3, g3o);
    bn_stats_part<<<NPART, CH, 0, stream>>>(g3o, psum, psq, NNODES, CH);
    bn_finalize<<<1, 64, 0, stream>>>(psum, psq, g3, be3, bnsc, bnsh, CH,
                                      1.0f / NNODES);
    {
        size_t total4 = (size_t)NNODES * CH / 4;
        bn_apply<<<(int)((total4 + 255) / 256), 256, 0, stream>>>(
            g3o, bnsc, bnsh, total4, CH - 1);
    }

    // ---- Fused global mean pool + final linear
    pool_linear<<<NG, 256, 0, stream>>>(g3o, goff, linW, linb, out);
}

// Round 10
// 421.785 us; speedup vs baseline: 1.6196x; 1.0017x over previous
//
#include <hip/hip_runtime.h>
#include <hip/hip_bf16.h>
#include <math.h>

// Problem constants (from reference)
#define NNODES 10000
#define MPAD   10112    // 79 * 128
#define EDGES  160000
#define EPLUS  170000   // EDGES + NNODES self-loops
#define FIN    512
#define HEADS8 8
#define CH     64
#define HC     512      // HEADS8*CH
#define NG     64       // graphs
#define NCLS   64
#define NPART  128      // bn partial blocks

typedef _Float16 f16x8 __attribute__((ext_vector_type(8)));
typedef _Float16 f16x4 __attribute__((ext_vector_type(4)));
typedef _Float16 f16x2 __attribute__((ext_vector_type(2)));
typedef float    f32x4 __attribute__((ext_vector_type(4)));

#define GLD_LDS16(g, l)                                                        \
    __builtin_amdgcn_global_load_lds(                                          \
        (const __attribute__((address_space(1))) void*)(g),                    \
        (__attribute__((address_space(3))) void*)(l), 16, 0, 0)

// ---------------------------------------------------------------------------
// Fused prep: [0,665) dst-degree histogram + graph offsets;
//             [665,5665) fp32->fp16 convert of x_in;
//             [5665,...) 4 weight transposes (fp32 KxN -> fp16 NxK)
// ---------------------------------------------------------------------------
#define PREP_CNT  665
#define PREP_CONV 5000   // 10000*512/4 / 256
__global__ void prep_all(const int* __restrict__ ei, int* __restrict__ deg,
                         const int* __restrict__ batch, int* __restrict__ goff,
                         const float* __restrict__ x_in, _Float16* __restrict__ x16,
                         const float* __restrict__ Wa, const float* __restrict__ Wb,
                         const float* __restrict__ Wc, const float* __restrict__ Wd,
                         _Float16* __restrict__ Ta, _Float16* __restrict__ Tb,
                         _Float16* __restrict__ Tc, _Float16* __restrict__ Td)
{
    const int b   = blockIdx.x;
    const int tid = threadIdx.x;
    if (b < PREP_CNT) {
        int e = b * 256 + tid;
        if (e < NNODES) {
            int bb = batch[e];
            int bprev = (e == 0) ? -1 : batch[e - 1];
            for (int g = bprev + 1; g <= bb; ++g) goff[g] = e;
            if (e == NNODES - 1)
                for (int g = bb + 1; g <= NG; ++g) goff[g] = NNODES;
        }
        if (e >= EPLUS) return;
        int dst = (e < EDGES) ? ei[EDGES + e] : (e - EDGES);
        atomicAdd(&deg[dst], 1);
    } else if (b < PREP_CNT + PREP_CONV) {
        int i = (b - PREP_CNT) * 256 + tid;
        float4 v = ((const float4*)x_in)[i];
        f16x4 o;
        o[0] = (_Float16)v.x; o[1] = (_Float16)v.y;
        o[2] = (_Float16)v.z; o[3] = (_Float16)v.w;
        ((f16x4*)x16)[i] = o;
    } else {
        int tb = b - (PREP_CNT + PREP_CONV);
        int z  = tb >> 8;            // 0..3
        int rem = tb & 255;
        int bxi = rem & 15, byi = rem >> 4;
        if (z == 3 && bxi >= 2) return;   // W3 has only 64 cols
        const float* W = (z == 0) ? Wa : (z == 1) ? Wb : (z == 2) ? Wc : Wd;
        _Float16*    T = (z == 0) ? Ta : (z == 1) ? Tb : (z == 2) ? Tc : Td;
        const int ldW = (z == 3) ? 64 : 512;
        __shared__ float t[32][33];
        int bx = bxi * 32, by = byi * 32;
        int tx = tid & 31, ty = tid >> 5;   // 32 x 8
        #pragma unroll
        for (int i = 0; i < 32; i += 8)
            t[ty + i][tx] = W[(size_t)(by + ty + i) * ldW + bx + tx];
        __syncthreads();
        #pragma unroll
        for (int i = 0; i < 32; i += 8)
            T[(size_t)(bx + ty + i) * 512 + by + tx] = (_Float16)t[tx][ty + i];
    }
}

__global__ void exscan_deg(const int* __restrict__ deg, int* __restrict__ off,
                           int* __restrict__ cursor)
{
    __shared__ int partial[256];
    const int tid = threadIdx.x;
    const int chunk = (NNODES + 255) / 256; // 40
    int begin = tid * chunk;
    int end   = begin + chunk; if (end > NNODES) end = NNODES;
    if (begin > NNODES) begin = NNODES;
    int s = 0;
    for (int i = begin; i < end; ++i) s += deg[i];
    partial[tid] = s;
    __syncthreads();
    for (int o = 1; o < 256; o <<= 1) {
        int v = (tid >= o) ? partial[tid - o] : 0;
        __syncthreads();
        partial[tid] += v;
        __syncthreads();
    }
    int run = (tid > 0) ? partial[tid - 1] : 0;  // exclusive prefix
    for (int i = begin; i < end; ++i) {
        off[i] = run; cursor[i] = run; run += deg[i];
    }
    if (tid == 255) off[NNODES] = run; // == EPLUS
}

__global__ void scatter_edges(const int* __restrict__ ei, int* __restrict__ cursor,
                              int* __restrict__ csr)
{
    int e = blockIdx.x * blockDim.x + threadIdx.x;
    if (e >= EPLUS) return;
    int srcN, dstN;
    if (e < EDGES) { srcN = ei[e]; dstN = ei[EDGES + e]; }
    else           { srcN = dstN = e - EDGES; }
    int pos = atomicAdd(&cursor[dstN], 1);
    csr[pos] = srcN;
}

// ---------------------------------------------------------------------------
// fp16 MFMA GEMM: C[M,N] = A16[M,K] @ Bt16[N,K]^T (+bias), 128x64 tile.
// Optional fused per-head attention scores (64-col tile == one head).
// ---------------------------------------------------------------------------
__global__ __launch_bounds__(256) void gemm_f16_mfma(
    const _Float16* __restrict__ A16, const _Float16* __restrict__ Bt16,
    const float* __restrict__ bias, _Float16* __restrict__ C16,
    float* __restrict__ ssrc, float* __restrict__ sdst,
    const float* __restrict__ a_s, const float* __restrict__ a_d,
    int M, int Nn, int K)
{
    __shared__ _Float16 As[128 * 32] __attribute__((aligned(16)));
    __shared__ _Float16 Bs[64 * 32]  __attribute__((aligned(16)));
    __shared__ float sS[2][128];
    __shared__ float sD[2][128];
    const int tid  = threadIdx.x;
    const int wave = tid >> 6;
    const int lane = tid & 63;
    const int row0 = blockIdx.y * 128;
    const int col0 = blockIdx.x * 64;
    const int wy = wave >> 1, wx = wave & 1;

    const int lrow = lane >> 2;
    const int lk   = (lane & 3) * 8;

    f32x4 acc[4][2] = {};

    for (int k0 = 0; k0 < K; k0 += 32) {
        if (k0) __syncthreads();
        #pragma unroll
        for (int r = 0; r < 2; ++r) {
            const int chunk = r * 4 + wave;
            const int trow  = chunk * 16 + lrow;
            GLD_LDS16(A16 + (size_t)(row0 + trow) * K + k0 + lk,
                      &As[chunk * 512]);
        }
        {
            const int trow = wave * 16 + lrow;
            GLD_LDS16(Bt16 + (size_t)(col0 + trow) * K + k0 + lk,
                      &Bs[wave * 512]);
        }
        __syncthreads();

        const int quad = lane >> 4;
        const int l16  = lane & 15;
        f16x8 af[4], bf[2];
        #pragma unroll
        for (int m = 0; m < 4; ++m)
            af[m] = *(const f16x8*)&As[(wy * 64 + m * 16 + l16) * 32 + quad * 8];
        #pragma unroll
        for (int n = 0; n < 2; ++n)
            bf[n] = *(const f16x8*)&Bs[(wx * 32 + n * 16 + l16) * 32 + quad * 8];
        #pragma unroll
        for (int m = 0; m < 4; ++m)
            #pragma unroll
            for (int n = 0; n < 2; ++n)
                acc[m][n] = __builtin_amdgcn_mfma_f32_16x16x32_f16(
                    af[m], bf[n], acc[m][n], 0, 0, 0);
    }

    const int quad = lane >> 4;
    const int l16  = lane & 15;
    #pragma unroll
    for (int m = 0; m < 4; ++m) {
        #pragma unroll
        for (int n = 0; n < 2; ++n) {
            const int col = col0 + wx * 32 + n * 16 + l16;
            const float bv = bias ? bias[col] : 0.0f;
            #pragma unroll
            for (int r = 0; r < 4; ++r) {
                const int row = row0 + wy * 64 + m * 16 + quad * 4 + r;
                if (row < M)
                    C16[(size_t)row * Nn + col] = (_Float16)(acc[m][n][r] + bv);
            }
        }
    }

    if (ssrc) {   // fused per-head scores (bias-less layer GEMMs)
        float a_sv[2], a_dv[2];
        #pragma unroll
        for (int n = 0; n < 2; ++n) {
            const int col = col0 + wx * 32 + n * 16 + l16;
            a_sv[n] = a_s[col & 511];
            a_dv[n] = a_d[col & 511];
        }
        #pragma unroll
        for (int m = 0; m < 4; ++m) {
            #pragma unroll
            for (int r = 0; r < 4; ++r) {
                float vs = acc[m][0][r] * a_sv[0] + acc[m][1][r] * a_sv[1];
                float vd = acc[m][0][r] * a_dv[0] + acc[m][1][r] * a_dv[1];
                vs += __shfl_xor(vs, 1); vs += __shfl_xor(vs, 2);
                vs += __shfl_xor(vs, 4); vs += __shfl_xor(vs, 8);
                vd += __shfl_xor(vd, 1); vd += __shfl_xor(vd, 2);
                vd += __shfl_xor(vd, 4); vd += __shfl_xor(vd, 8);
                if (l16 == 0) {
                    const int lr = wy * 64 + m * 16 + quad * 4 + r;
                    sS[wx][lr] = vs;
                    sD[wx][lr] = vd;
                }
            }
        }
        __syncthreads();
        if (wx == 0 && l16 == 0) {
            const int head = blockIdx.x;   // Nn==512: col tile == head
            #pragma unroll
            for (int m = 0; m < 4; ++m)
                #pragma unroll
                for (int r = 0; r < 4; ++r) {
                    const int lr = wy * 64 + m * 16 + quad * 4 + r;
                    const int row = row0 + lr;
                    if (row < M) {
                        ssrc[(size_t)row * HEADS8 + head] = sS[0][lr] + sS[1][lr];
                        sdst[(size_t)row * HEADS8 + head] = sD[0][lr] + sD[1][lr];
                    }
                }
        }
    }
}

// ---------------------------------------------------------------------------
// fp16 MFMA GEMM, N=64 (layer 3) with fused NH=1 scores.
// ---------------------------------------------------------------------------
__global__ __launch_bounds__(256) void gemm_f16_mfma_n64(
    const _Float16* __restrict__ A16, const _Float16* __restrict__ Bt16,
    _Float16* __restrict__ C16,
    float* __restrict__ ssrc, float* __restrict__ sdst,
    const float* __restrict__ a_s, const float* __restrict__ a_d, int M)
{
    __shared__ _Float16 As[64 * 32] __attribute__((aligned(16)));
    __shared__ _Float16 Bs[64 * 32] __attribute__((aligned(16)));
    __shared__ float sS[2][64];
    __shared__ float sD[2][64];
    const int tid  = threadIdx.x;
    const int wave = tid >> 6;
    const int lane = tid & 63;
    const int row0 = blockIdx.x * 64;
    const int wy = wave >> 1, wx = wave & 1;

    const int lrow = lane >> 2;
    const int lk   = (lane & 3) * 8;

    f32x4 acc[2][2] = {};

    for (int k0 = 0; k0 < 512; k0 += 32) {
        if (k0) __syncthreads();
        {
            const int trow = wave * 16 + lrow;
            GLD_LDS16(A16 + (size_t)(row0 + trow) * 512 + k0 + lk, &As[wave * 512]);
            GLD_LDS16(Bt16 + (size_t)trow * 512 + k0 + lk, &Bs[wave * 512]);
        }
        __syncthreads();

        const int quad = lane >> 4;
        const int l16  = lane & 15;
        f16x8 af[2], bf[2];
        #pragma unroll
        for (int m = 0; m < 2; ++m)
            af[m] = *(const f16x8*)&As[(wy * 32 + m * 16 + l16) * 32 + quad * 8];
        #pragma unroll
        for (int n = 0; n < 2; ++n)
            bf[n] = *(const f16x8*)&Bs[(wx * 32 + n * 16 + l16) * 32 + quad * 8];
        #pragma unroll
        for (int m = 0; m < 2; ++m)
            #pragma unroll
            for (int n = 0; n < 2; ++n)
                acc[m][n] = __builtin_amdgcn_mfma_f32_16x16x32_f16(
                    af[m], bf[n], acc[m][n], 0, 0, 0);
    }

    const int quad = lane >> 4;
    const int l16  = lane & 15;
    #pragma unroll
    for (int m = 0; m < 2; ++m)
        #pragma unroll
        for (int n = 0; n < 2; ++n) {
            const int col = wx * 32 + n * 16 + l16;
            #pragma unroll
            for (int r = 0; r < 4; ++r) {
                const int row = row0 + wy * 32 + m * 16 + quad * 4 + r;
                if (row < M)
                    C16[(size_t)row * 64 + col] = (_Float16)acc[m][n][r];
            }
        }

    // fused scores (heads=1)
    {
        float a_sv[2], a_dv[2];
        #pragma unroll
        for (int n = 0; n < 2; ++n) {
            const int col = wx * 32 + n * 16 + l16;
            a_sv[n] = a_s[col];
            a_dv[n] = a_d[col];
        }
        #pragma unroll
        for (int m = 0; m < 2; ++m)
            #pragma unroll
            for (int r = 0; r < 4; ++r) {
                float vs = acc[m][0][r] * a_sv[0] + acc[m][1][r] * a_sv[1];
                float vd = acc[m][0][r] * a_dv[0] + acc[m][1][r] * a_dv[1];
                vs += __shfl_xor(vs, 1); vs += __shfl_xor(vs, 2);
                vs += __shfl_xor(vs, 4); vs += __shfl_xor(vs, 8);
                vd += __shfl_xor(vd, 1); vd += __shfl_xor(vd, 2);
                vd += __shfl_xor(vd, 4); vd += __shfl_xor(vd, 8);
                if (l16 == 0) {
                    const int lr = wy * 32 + m * 16 + quad * 4 + r;
                    sS[wx][lr] = vs;
                    sD[wx][lr] = vd;
                }
            }
        __syncthreads();
        if (wx == 0 && l16 == 0) {
            #pragma unroll
            for (int m = 0; m < 2; ++m)
                #pragma unroll
                for (int r = 0; r < 4; ++r) {
                    const int lr = wy * 32 + m * 16 + quad * 4 + r;
                    const int row = row0 + lr;
                    if (row < M) {
                        ssrc[row] = sS[0][lr] + sS[1][lr];
                        sdst[row] = sD[0][lr] + sD[1][lr];
                    }
                }
        }
    }
}

// ---------------------------------------------------------------------------
// Segment-softmax aggregation, NH=8 fp16, single pass; f16 output.
// Edge loop UNROLLED x4: 4 independent gathers in flight per wave (MLP).
// ---------------------------------------------------------------------------
__global__ __launch_bounds__(64) void gat_aggregate8(
    const _Float16* __restrict__ Hf, const float* __restrict__ ssrc,
    const float* __restrict__ sdst, const int* __restrict__ off,
    const int* __restrict__ csr, const float* __restrict__ bias,
    _Float16* __restrict__ out)
{
    const int n    = blockIdx.x;
    const int lane = threadIdx.x;
    const int head = lane >> 3;
    const int e0 = off[n], e1 = off[n + 1];

    float4 sd0 = ((const float4*)(sdst + n * 8))[0];
    float4 sd1 = ((const float4*)(sdst + n * 8))[1];
    float sd[8] = {sd0.x, sd0.y, sd0.z, sd0.w, sd1.x, sd1.y, sd1.z, sd1.w};

    __shared__ float exL[64 * 8];
    __shared__ int   srcL[64];
    float acc[8]  = {};
    float ssum[8] = {};
    for (int base = e0; base < e1; base += 64) {
        int cnt = e1 - base; if (cnt > 64) cnt = 64;
        if (lane < cnt) {
            int s = csr[base + lane];
            srcL[lane] = s;
            float4 s0 = ((const float4*)(ssrc + s * 8))[0];
            float4 s1 = ((const float4*)(ssrc + s * 8))[1];
            float lv[8] = {s0.x, s0.y, s0.z, s0.w, s1.x, s1.y, s1.z, s1.w};
            #pragma unroll
            for (int h = 0; h < 8; ++h) {
                float l = lv[h] + sd[h];
                l = (l > 0.f) ? l : 0.2f * l;
                float ex = __expf(l);
                exL[lane * 8 + h] = ex;
                ssum[h] += ex;
            }
        }
        __syncthreads();
        int j = 0;
        for (; j + 4 <= cnt; j += 4) {
            const int s0 = srcL[j],     s1 = srcL[j + 1];
            const int s2 = srcL[j + 2], s3 = srcL[j + 3];
            f16x8 h0 = *(const f16x8*)(Hf + (size_t)s0 * HC + lane * 8);
            f16x8 h1 = *(const f16x8*)(Hf + (size_t)s1 * HC + lane * 8);
            f16x8 h2 = *(const f16x8*)(Hf + (size_t)s2 * HC + lane * 8);
            f16x8 h3 = *(const f16x8*)(Hf + (size_t)s3 * HC + lane * 8);
            const float a0 = exL[(j)     * 8 + head];
            const float a1 = exL[(j + 1) * 8 + head];
            const float a2 = exL[(j + 2) * 8 + head];
            const float a3 = exL[(j + 3) * 8 + head];
            #pragma unroll
            for (int c = 0; c < 8; ++c) {
                acc[c] = fmaf(a0, (float)h0[c], acc[c]);
                acc[c] = fmaf(a1, (float)h1[c], acc[c]);
                acc[c] = fmaf(a2, (float)h2[c], acc[c]);
                acc[c] = fmaf(a3, (float)h3[c], acc[c]);
            }
        }
        for (; j < cnt; ++j) {
            const int s = srcL[j];
            f16x8 hv = *(const f16x8*)(Hf + (size_t)s * HC + lane * 8);
            const float al = exL[j * 8 + head];
            #pragma unroll
            for (int c = 0; c < 8; ++c)
                acc[c] = fmaf(al, (float)hv[c], acc[c]);
        }
        __syncthreads();
    }
    #pragma unroll
    for (int h = 0; h < 8; ++h)
        #pragma unroll
        for (int o = 1; o < 64; o <<= 1)
            ssum[h] += __shfl_xor(ssum[h], o);

    const float inv = 1.0f / (ssum[head] + 1e-16f);
    const float* bp = bias + lane * 8;
    f16x8 ov;
    #pragma unroll
    for (int c = 0; c < 8; ++c)
        ov[c] = (_Float16)(acc[c] * inv + bp[c]);
    *(f16x8*)(out + (size_t)n * HC + lane * 8) = ov;
}

// NH=1 fp16 aggregate (layer 3), single pass, lane = channel; unrolled x4
__global__ __launch_bounds__(64) void gat_aggregate1(
    const _Float16* __restrict__ Hf, const float* __restrict__ ssrc,
    const float* __restrict__ sdst, const int* __restrict__ off,
    const int* __restrict__ csr, const float* __restrict__ bias,
    float* __restrict__ out)
{
    const int n    = blockIdx.x;
    const int lane = threadIdx.x;
    const int e0 = off[n], e1 = off[n + 1];
    const float sd = sdst[n];

    __shared__ float exL[64];
    __shared__ int   srcL[64];
    float acc = 0.f, ssum = 0.f;
    for (int base = e0; base < e1; base += 64) {
        int cnt = e1 - base; if (cnt > 64) cnt = 64;
        if (lane < cnt) {
            int s = csr[base + lane];
            srcL[lane] = s;
            float l = ssrc[s] + sd;
            l = (l > 0.f) ? l : 0.2f * l;
            float ex = __expf(l);
            exL[lane] = ex;
            ssum += ex;
        }
        __syncthreads();
        int j = 0;
        for (; j + 4 <= cnt; j += 4) {
            const int s0 = srcL[j],     s1 = srcL[j + 1];
            const int s2 = srcL[j + 2], s3 = srcL[j + 3];
            float h0 = (float)Hf[(size_t)s0 * 64 + lane];
            float h1 = (float)Hf[(size_t)s1 * 64 + lane];
            float h2 = (float)Hf[(size_t)s2 * 64 + lane];
            float h3 = (float)Hf[(size_t)s3 * 64 + lane];
            acc = fmaf(exL[j],     h0, acc);
            acc = fmaf(exL[j + 1], h1, acc);
            acc = fmaf(exL[j + 2], h2, acc);
            acc = fmaf(exL[j + 3], h3, acc);
        }
        for (; j < cnt; ++j)
            acc = fmaf(exL[j], (float)Hf[(size_t)srcL[j] * 64 + lane], acc);
        __syncthreads();
    }
    #pragma unroll
    for (int o = 1; o < 64; o <<= 1)
        ssum += __shfl_xor(ssum, o);

    out[(size_t)n * 64 + lane] = acc / (ssum + 1e-16f) + bias[lane];
}

// ---------------------------------------------------------------------------
// BatchNorm (f16 activations): partial sums -> finalize -> vectorized apply
// ---------------------------------------------------------------------------
__global__ void bn_stats_f16(const _Float16* __restrict__ x,
                             float* __restrict__ psum, float* __restrict__ psq,
                             int rows)
{
    const int c2  = threadIdx.x;   // owns cols 2*c2, 2*c2+1
    const int blk = blockIdx.x;
    float s0 = 0.f, q0 = 0.f, s1 = 0.f, q1 = 0.f;
    for (int r = blk; r < rows; r += NPART) {
        f16x2 v = *(const f16x2*)(x + (size_t)r * HC + c2 * 2);
        float a = (float)v[0], b = (float)v[1];
        s0 += a; q0 += a * a;
        s1 += b; q1 += b * b;
    }
    psum[(size_t)blk * HC + c2 * 2]     = s0;
    psum[(size_t)blk * HC + c2 * 2 + 1] = s1;
    psq [(size_t)blk * HC + c2 * 2]     = q0;
    psq [(size_t)blk * HC + c2 * 2 + 1] = q1;
}

// fp32 stats (layer 3, cols=64, blockDim=64)
__global__ void bn_stats_part(const float* __restrict__ x,
                              float* __restrict__ psum, float* __restrict__ psq,
                              int rows, int cols)
{
    const int c   = threadIdx.x;
    const int blk = blockIdx.x;
    float s = 0.f, sq = 0.f;
    for (int r = blk; r < rows; r += NPART) {
        float v = x[(size_t)r * cols + c];
        s += v; sq += v * v;
    }
    psum[(size_t)blk * cols + c] = s;
    psq [(size_t)blk * cols + c] = sq;
}

__global__ void bn_finalize(const float* __restrict__ psum,
                            const float* __restrict__ psq,
                            const float* __restrict__ g, const float* __restrict__ be,
                            float* __restrict__ scale, float* __restrict__ shift,
                            int cols, float invN)
{
    int c = blockIdx.x * blockDim.x + threadIdx.x;
    if (c >= cols) return;
    float s = 0.f, sq = 0.f;
    for (int p = 0; p < NPART; ++p) {
        s  += psum[(size_t)p * cols + c];
        sq += psq [(size_t)p * cols + c];
    }
    float mu  = s * invN;
    float var = sq * invN - mu * mu;
    float istd = 1.0f / sqrtf(var + 1e-5f);
    float sc = g[c] * istd;
    scale[c] = sc;
    shift[c] = be[c] - mu * sc;
}

// f16 in, f16 residual, f16 out: v = elu(x*scale + shift) + res
__global__ void bn_apply16(const _Float16* __restrict__ xin,
                           const _Float16* __restrict__ res,
                           const float* __restrict__ scale,
                           const float* __restrict__ shift,
                           _Float16* __restrict__ out, size_t total4, int colmask)
{
    size_t i = (size_t)blockIdx.x * blockDim.x + threadIdx.x;
    if (i >= total4) return;
    int c = (int)((i * 4) & (size_t)colmask);
    f16x4 xv = ((const f16x4*)xin)[i];
    float4 sc = *(const float4*)(scale + c);
    float4 sh = *(const float4*)(shift + c);
    f16x4 rv = ((const f16x4*)res)[i];
    float v0 = (float)xv[0] * sc.x + sh.x;
    float v1 = (float)xv[1] * sc.y + sh.y;
    float v2 = (float)xv[2] * sc.z + sh.z;
    float v3 = (float)xv[3] * sc.w + sh.w;
    v0 = (v0 > 0.f) ? v0 : expm1f(v0);
    v1 = (v1 > 0.f) ? v1 : expm1f(v1);
    v2 = (v2 > 0.f) ? v2 : expm1f(v2);
    v3 = (v3 > 0.f) ? v3 : expm1f(v3);
    f16x4 o;
    o[0] = (_Float16)(v0 + (float)rv[0]);
    o[1] = (_Float16)(v1 + (float)rv[1]);
    o[2] = (_Float16)(v2 + (float)rv[2]);
    o[3] = (_Float16)(v3 + (float)rv[3]);
    ((f16x4*)out)[i] = o;
}

// fp32 in-place apply (layer 3: no elu, no residual)
__global__ void bn_apply(float* __restrict__ x,
                         const float* __restrict__ scale, const float* __restrict__ shift,
                         size_t total4, int colmask)
{
    size_t i = (size_t)blockIdx.x * blockDim.x + threadIdx.x;
    if (i >= total4) return;
    int c = (int)((i * 4) & (size_t)colmask);
    float4 xv = ((const float4*)x)[i];
    float4 sc = *(const float4*)(scale + c);
    float4 sh = *(const float4*)(shift + c);
    ((float4*)x)[i] = make_float4(xv.x * sc.x + sh.x, xv.y * sc.y + sh.y,
                                  xv.z * sc.z + sh.z, xv.w * sc.w + sh.w);
}

// ---------------------------------------------------------------------------
// Fused global-mean-pool + final linear (one block per graph)
// ---------------------------------------------------------------------------
__global__ __launch_bounds__(256) void pool_linear(
    const float* __restrict__ x, const int* __restrict__ goff,
    const float* __restrict__ W, const float* __restrict__ b,
    float* __restrict__ out)
{
    const int g    = blockIdx.x;
    const int lane = threadIdx.x & 63;   // channel
    const int wave = threadIdx.x >> 6;   // 0..3
    const int r0 = goff[g], r1 = goff[g + 1];
    float s = 0.f;
    for (int r = r0 + wave; r < r1; r += 4)
        s += x[(size_t)r * CH + lane];
    __shared__ float red[4][CH];
    __shared__ float mean_l[CH];
    red[wave][lane] = s;
    __syncthreads();
    if (wave == 0) {
        float tot = red[0][lane] + red[1][lane] + red[2][lane] + red[3][lane];
        float cnt = (float)(r1 - r0);
        mean_l[lane] = tot / fmaxf(cnt, 1.0f);
    }
    __syncthreads();
    if (threadIdx.x < NCLS) {
        const int j = threadIdx.x;
        float acc = b[j];
        for (int c = 0; c < CH; ++c)
            acc = fmaf(mean_l[c], W[c * NCLS + j], acc);
        out[g * NCLS + j] = acc;
    }
}

// ---------------------------------------------------------------------------
// Host launcher
// ---------------------------------------------------------------------------
extern "C" void kernel_launch(void* const* d_in, const int* in_sizes, int n_in,
                              void* d_out, int out_size, void* d_ws, size_t ws_size,
                              hipStream_t stream)
{
    const float* x_in  = (const float*)d_in[0];
    const int*   ei    = (const int*)  d_in[1];
    const int*   batch = (const int*)  d_in[2];
    const float* enc_W = (const float*)d_in[3];
    const float* enc_b = (const float*)d_in[4];
    const float* W1  = (const float*)d_in[5];
    const float* as1 = (const float*)d_in[6];
    const float* ad1 = (const float*)d_in[7];
    const float* b1  = (const float*)d_in[8];
    const float* g1  = (const float*)d_in[9];
    const float* be1 = (const float*)d_in[10];
    const float* W2  = (const float*)d_in[11];
    const float* as2 = (const float*)d_in[12];
    const float* ad2 = (const float*)d_in[13];
    const float* b2  = (const float*)d_in[14];
    const float* g2  = (const float*)d_in[15];
    const float* be2 = (const float*)d_in[16];
    const float* W3  = (const float*)d_in[17];
    const float* as3 = (const float*)d_in[18];
    const float* ad3 = (const float*)d_in[19];
    const float* b3  = (const float*)d_in[20];
    const float* g3  = (const float*)d_in[21];
    const float* be3 = (const float*)d_in[22];
    const float* linW = (const float*)d_in[23];
    const float* linb = (const float*)d_in[24];
    float* out = (float*)d_out;

    char* ws = (char*)d_ws;
    size_t off_b = 0;
    auto alloc = [&](size_t bytes) -> void* {
        void* p = ws + off_b;
        off_b = (off_b + bytes + 255) & ~(size_t)255;
        return p;
    };
    _Float16* f16A   = (_Float16*)alloc((size_t)MPAD * HC * 2);   // act buf A
    _Float16* f16B   = (_Float16*)alloc((size_t)MPAD * HC * 2);   // act buf B
    _Float16* H16    = (_Float16*)alloc((size_t)NNODES * HC * 2); // GAT features
    _Float16* g16    = (_Float16*)alloc((size_t)NNODES * HC * 2); // aggregate out
    _Float16* h3_16  = (_Float16*)alloc((size_t)NNODES * CH * 2);
    float*    g3o    = (float*)alloc((size_t)NNODES * CH * 4);
    _Float16* encWt  = (_Float16*)alloc((size_t)HC * FIN * 2);
    _Float16* W1t    = (_Float16*)alloc((size_t)HC * HC * 2);
    _Float16* W2t    = (_Float16*)alloc((size_t)HC * HC * 2);
    _Float16* W3t    = (_Float16*)alloc((size_t)CH * HC * 2);
    float* ssrc   = (float*)alloc((size_t)NNODES * HEADS8 * 4);
    float* sdst   = (float*)alloc((size_t)NNODES * HEADS8 * 4);
    int*   deg    = (int*)  alloc((size_t)NNODES * 4);
    int*   offp   = (int*)  alloc((size_t)(NNODES + 1) * 4);
    int*   cursor = (int*)  alloc((size_t)NNODES * 4);
    int*   csr    = (int*)  alloc((size_t)EPLUS * 4);
    int*   goff   = (int*)  alloc((size_t)(NG + 1) * 4);
    float* psum   = (float*)alloc((size_t)NPART * HC * 4);
    float* psq    = (float*)alloc((size_t)NPART * HC * 4);
    float* bnsc   = (float*)alloc(HC * 4);
    float* bnsh   = (float*)alloc(HC * 4);

    // ---- Prep: histogram+goff, x fp16 convert, weight transposes (1 kernel)
    hipMemsetAsync(deg, 0, (size_t)NNODES * 4, stream);
    prep_all<<<PREP_CNT + PREP_CONV + 1024, 256, 0, stream>>>(
        ei, deg, batch, goff, x_in, f16A, enc_W, W1, W2, W3,
        encWt, W1t, W2t, W3t);
    exscan_deg<<<1, 256, 0, stream>>>(deg, offp, cursor);
    scatter_edges<<<(EPLUS + 255) / 256, 256, 0, stream>>>(ei, cursor, csr);

    const dim3 mfma_grid(HC / 64, MPAD / 128);   // (8, 79) = 632 blocks

    // ---- Encoder: f16B = f16(x_in @ enc_W + enc_b)
    gemm_f16_mfma<<<mfma_grid, 256, 0, stream>>>(
        f16A, encWt, enc_b, f16B, nullptr, nullptr, nullptr, nullptr,
        NNODES, HC, FIN);

    // ---- GAT layers 1-2 (scores fused into GEMM; fp16 activation pipeline)
    auto run_layer = [&](const _Float16* a16, const _Float16* wt,
                         const _Float16* res16, _Float16* out16,
                         const float* a_s, const float* a_d,
                         const float* bconv, const float* gg, const float* bb) {
        gemm_f16_mfma<<<mfma_grid, 256, 0, stream>>>(
            a16, wt, nullptr, H16, ssrc, sdst, a_s, a_d, NNODES, HC, HC);
        gat_aggregate8<<<NNODES, 64, 0, stream>>>(H16, ssrc, sdst, offp, csr,
                                                  bconv, g16);
        bn_stats_f16<<<NPART, 256, 0, stream>>>(g16, psum, psq, NNODES);
        bn_finalize<<<2, 256, 0, stream>>>(psum, psq, gg, bb, bnsc, bnsh, HC,
                                           1.0f / NNODES);
        size_t total4 = (size_t)NNODES * HC / 4;
        bn_apply16<<<(int)((total4 + 255) / 256), 256, 0, stream>>>(
            g16, res16, bnsc, bnsh, out16, total4, HC - 1);
    };

    // Layer 1: A=f16B, residual f16B, out f16A
    run_layer(f16B, W1t, f16B, f16A, as1, ad1, b1, g1, be1);
    // Layer 2: A=f16A, residual f16A, out f16B
    run_layer(f16A, W2t, f16A, f16B, as2, ad2, b2, g2, be2);

    // ---- Layer 3 (heads=1, C=64): fp16 MFMA GEMM with fused scores
    gemm_f16_mfma_n64<<<MPAD / 64, 256, 0, stream>>>(f16B, W3t, h3_16,
                                                     ssrc, sdst, as3, ad3,
                                                     NNODES);
    gat_aggregate1<<<NNODES, 64, 0, stream>>>(h3_16, ssrc, sdst, offp, csr,
                                              b3, g3o);
    bn_stats_part<<<NPART, CH, 0, stream>>>(g3o, psum, psq, NNODES, CH);
    bn_finalize<<<1, 64, 0, stream>>>(psum, psq, g3, be3, bnsc, bnsh, CH,
                                      1.0f / NNODES);
    {
        size_t total4 = (size_t)NNODES * CH / 4;
        bn_apply<<<(int)((total4 + 255) / 256), 256, 0, stream>>>(
            g3o, bnsc, bnsh, total4, CH - 1);
    }

    // ---- Fused global mean pool + final linear
    pool_linear<<<NG, 256, 0, stream>>>(g3o, goff, linW, linb, out);
}